// Round 7
// baseline (323.463 us; speedup 1.0000x reference)
//
#include <hip/hip_runtime.h>
#include <hip/hip_bf16.h>

// GCN 2-layer, two-pass dst-radix-sort + per-node wave gathers:
//   h1 = bf16( bf16(x) @ bf16(W1) )     (MFMA 16x16x32, [N,64])
//   per-node hist + global scan -> off[] ; gcursor[b] = off[b*256]
//   pass1: partition edges into buckets of 256 dst (dst>>8), LDS-staged runs
//   pass2: single-pass per-bucket scatter by dst&255 -> es2 (dst-sorted)
//   gather1 (batched): wave gathers 16 nodes -> LDS bf16 tile; layer2 via MFMA
//   gather2 (wave/node, 16 lanes/edge): out = segsum(h2[src]*w) + b2 (f32)

typedef unsigned short u16;
typedef unsigned int uint;
typedef short short8 __attribute__((ext_vector_type(8)));
typedef float floatx4 __attribute__((ext_vector_type(4)));

static __device__ __forceinline__ float bf2f(u16 v) {
    return __uint_as_float(((unsigned int)v) << 16);
}
static __device__ __forceinline__ u16 f2bf(float f) {
    unsigned int u = __float_as_uint(f);
    return (u16)((u + 0x7fff + ((u >> 16) & 1)) >> 16);   // RNE
}

#define F4C(v, j) ((j)==0?(v).x:((j)==1?(v).y:((j)==2?(v).z:(v).w)))

// ---------------- g1_mfma: h1 = x @ W1 via bf16 MFMA ----------------
__global__ __launch_bounds__(256, 4) void g1_mfma(
    const float* __restrict__ x, const float* __restrict__ W1,
    u16* __restrict__ h1, int N)
{
    __shared__ __align__(16) u16 xs[64][136];
    __shared__ __align__(16) u16 wf[4][4][64][8];      // [ntile][step][lane][j]
    const int tid  = threadIdx.x;
    const int row0 = blockIdx.x * 64;

    {   // stage W1 (128x64 f32) -> bf16, swizzled to B-fragment order
        const float4* W4 = (const float4*)W1;
        #pragma unroll
        for (int i = 0; i < 8; i++) {
            int idx = tid + i*256;
            int k = idx >> 4, n4 = (idx & 15) * 4;
            float4 v = W4[idx];
            int step = k >> 5, klane = (k >> 3) & 3, j = k & 7;
            #pragma unroll
            for (int c = 0; c < 4; c++) {
                int n = n4 + c;
                wf[n >> 4][step][klane*16 + (n & 15)][j] = f2bf(F4C(v, c));
            }
        }
    }
    {   // stage x tile -> bf16
        const float4* x4 = (const float4*)x;
        #pragma unroll
        for (int i = 0; i < 8; i++) {
            int idx = tid + i*256;
            int r = idx >> 5, kc = idx & 31;
            int gr = row0 + r;
            float4 v = make_float4(0.f,0.f,0.f,0.f);
            if (gr < N) v = x4[gr*32 + kc];
            ushort4 o;
            o.x = f2bf(v.x); o.y = f2bf(v.y); o.z = f2bf(v.z); o.w = f2bf(v.w);
            *(ushort4*)&xs[r][kc*4] = o;
        }
    }
    __syncthreads();

    const int wave = tid >> 6, lane = tid & 63;
    const int m = lane & 15, quad = lane >> 4;
    const int rw = wave * 16;

    floatx4 acc[4] = {(floatx4)(0.f), (floatx4)(0.f), (floatx4)(0.f), (floatx4)(0.f)};
    #pragma unroll
    for (int step = 0; step < 4; step++) {
        short8 a = *(const short8*)&xs[rw + m][step*32 + quad*8];
        #pragma unroll
        for (int nt = 0; nt < 4; nt++) {
            short8 b = *(const short8*)&wf[nt][step][lane][0];
            acc[nt] = __builtin_amdgcn_mfma_f32_16x16x32_bf16(a, b, acc[nt], 0, 0, 0);
        }
    }
    #pragma unroll
    for (int nt = 0; nt < 4; nt++) {
        #pragma unroll
        for (int r = 0; r < 4; r++) {
            int gr = row0 + rw + quad*4 + r;
            if (gr < N) h1[(size_t)gr*64 + nt*16 + m] = f2bf(acc[nt][r]);
        }
    }
}

// ---------------- per-node histogram ----------------
__global__ __launch_bounds__(256) void hist_kernel(
    const int* __restrict__ dst, int* __restrict__ counts, int E)
{
    int e = blockIdx.x * 256 + threadIdx.x;
    if (e < E) atomicAdd(&counts[dst[e]], 1);
}

// ---------------- hierarchical scan: counts -> off[0..N], gcursor ----------
__global__ __launch_bounds__(256) void scan_partial_kernel(
    const int* __restrict__ counts, int* __restrict__ partials, int N)
{
    __shared__ int s[256];
    int t = threadIdx.x;
    int i = blockIdx.x * 256 + t;
    s[t] = (i < N) ? counts[i] : 0;
    __syncthreads();
    for (int off = 128; off > 0; off >>= 1) {
        if (t < off) s[t] += s[t + off];
        __syncthreads();
    }
    if (t == 0) partials[blockIdx.x] = s[0];
}

__global__ __launch_bounds__(1024) void scan_top_kernel(
    const int* __restrict__ partials, int* __restrict__ partials_off, int B)
{
    __shared__ int s[1024];
    int t = threadIdx.x;
    int v = (t < B) ? partials[t] : 0;
    s[t] = v;
    __syncthreads();
    for (int off = 1; off < 1024; off <<= 1) {
        int add = (t >= off) ? s[t - off] : 0;
        __syncthreads();
        s[t] += add;
        __syncthreads();
    }
    if (t < B) partials_off[t] = s[t] - v;   // exclusive
}

__global__ __launch_bounds__(256) void scan_final_kernel(
    const int* __restrict__ counts, const int* __restrict__ partials_off,
    int* __restrict__ off, int* __restrict__ gcursor, int N)
{
    __shared__ int s[256];
    int t = threadIdx.x;
    int i = blockIdx.x * 256 + t;
    int v = (i < N) ? counts[i] : 0;
    s[t] = v;
    __syncthreads();
    for (int o = 1; o < 256; o <<= 1) {
        int add = (t >= o) ? s[t - o] : 0;
        __syncthreads();
        s[t] += add;
        __syncthreads();
    }
    int excl = s[t] - v;
    int base = partials_off[blockIdx.x];
    if (i < N) {
        off[i] = base + excl;
        if ((i & 255) == 0) gcursor[i >> 8] = base + excl;   // bucket run cursor
    }
    if (i == N-1) off[N] = base + excl + v;   // == E
}

// ---------------- pass1: LDS-staged scatter into bucket runs ----------
// entry: x = src | (dst&255)<<24 ; y = w bits
#define CHUNK 4096
#define PT 512
__global__ __launch_bounds__(512, 2) void partition_kernel(
    const int* __restrict__ src, const int* __restrict__ dst,
    const float* __restrict__ w, int* __restrict__ gcursor,
    int2* __restrict__ es, int E)
{
    __shared__ int2 stage[CHUNK];        // 32 KB
    __shared__ u16  stb[CHUNK];          // 8 KB
    __shared__ int  hist[512];
    __shared__ int  sc[512];
    __shared__ int  xscan[512], place[512], runbase[512];
    const int tid = threadIdx.x;
    const int base = blockIdx.x * CHUNK;
    const int nloc = min(CHUNK, E - base);

    hist[tid] = 0;
    __syncthreads();
    for (int i = tid; i < nloc; i += PT)
        atomicAdd(&hist[dst[base + i] >> 8], 1);
    __syncthreads();

    int v = hist[tid];
    sc[tid] = v;
    __syncthreads();
    for (int o = 1; o < 512; o <<= 1) {          // Hillis-Steele inclusive
        int add = (tid >= o) ? sc[tid - o] : 0;
        __syncthreads();
        sc[tid] += add;
        __syncthreads();
    }
    int ex = sc[tid] - v;
    xscan[tid] = ex;
    place[tid] = ex;
    __syncthreads();

    for (int i = tid; i < nloc; i += PT) {
        int d = dst[base + i];
        int b = d >> 8;
        int pos = atomicAdd(&place[b], 1);
        stage[pos] = make_int2(src[base + i] | ((d & 255) << 24),
                               __float_as_int(w[base + i]));
        stb[pos] = (u16)b;
    }
    __syncthreads();

    runbase[tid] = hist[tid] ? atomicAdd(&gcursor[tid], hist[tid]) : 0;
    __syncthreads();

    for (int i = tid; i < nloc; i += PT) {
        int b = stb[i];
        es[runbase[b] + (i - xscan[b])] = stage[i];
    }
}

// ------- pass2: per-bucket single-pass scatter by dst&255 -> es2 -------
__global__ __launch_bounds__(512) void sort2_kernel(
    const int2* __restrict__ es, const int* __restrict__ off,
    int2* __restrict__ es2, int N)
{
    __shared__ int cur[256];
    const int t = threadIdx.x;
    const int b = blockIdx.x;
    const int e0 = off[b << 8];
    const int e1 = off[min((b + 1) << 8, N)];
    if (t < 256) {
        int g = (b << 8) + t;
        cur[t] = (g < N) ? off[g] : e1;   // global positions
    }
    __syncthreads();
    for (int i = e0 + t; i < e1; i += 512) {
        int2 e = es[i];
        int pos = atomicAdd(&cur[((unsigned)e.x) >> 24], 1);
        es2[pos] = e;                     // scatter within 32 KB window
    }
}

// ------- gather1 batched: 64 nodes/block, wave gathers 16 nodes -> LDS bf16
//         then layer2 (relu(+b1) @ W2) via MFMA on the wave's own 16 rows ----
__global__ __launch_bounds__(256) void gather1_kernel(
    const u16* __restrict__ h1, const int2* __restrict__ es,
    const int* __restrict__ off, const float* __restrict__ b1,
    const float* __restrict__ W2, u16* __restrict__ h2, int N)
{
    __shared__ __align__(16) u16 ts[64][72];          // t rows, bf16 (144B rows)
    __shared__ __align__(16) u16 wf2[2][2][64][8];    // [ntile][step][lane][j]
    __shared__ float b1s[64];
    const int tid = threadIdx.x;

    {   // stage W2 (64x32 f32 = 512 float4) -> bf16 B-fragments, + b1
        const float4* s4 = (const float4*)W2;
        #pragma unroll
        for (int i = 0; i < 2; i++) {
            int idx = tid + i*256;
            float4 v = s4[idx];
            int k = idx >> 3, n4 = (idx & 7) * 4;
            int step = k >> 5, quad = (k >> 3) & 3, j = k & 7;
            #pragma unroll
            for (int c = 0; c < 4; c++) {
                int n = n4 + c;
                wf2[n >> 4][step][quad*16 + (n & 15)][j] = f2bf(F4C(v, c));
            }
        }
        if (tid < 16) ((float4*)b1s)[tid] = ((const float4*)b1)[tid];
    }
    __syncthreads();

    const int wave = tid >> 6, lane = tid & 63;
    const int h = lane >> 5, fl = lane & 31;
    const int node0 = blockIdx.x * 64 + wave * 16;
    const uint* h1u = (const uint*)h1;     // h1 row = 32 uints (64 bf16)
    uint* tsu = (uint*)&ts[0][0];          // rows of 36 uints

    #pragma unroll 1
    for (int i = 0; i < 16; i++) {
        const int d = node0 + i;
        float ax = 0.f, ay = 0.f;
        if (d < N) {                       // wave-uniform branch
            int pbeg = __builtin_amdgcn_readfirstlane(off[d]);
            int pend = __builtin_amdgcn_readfirstlane(off[d + 1]);
            int p = pbeg;
            for (; p + 8 <= pend; p += 8) {    // 8 edges/iter, 4 gathers in flight
                int2 e0 = es[p + h],     e1 = es[p + 2 + h];
                int2 e2 = es[p + 4 + h], e3 = es[p + 6 + h];
                uint v0 = h1u[(size_t)(e0.x & 0xFFFFFF) * 32 + fl];
                uint v1 = h1u[(size_t)(e1.x & 0xFFFFFF) * 32 + fl];
                uint v2 = h1u[(size_t)(e2.x & 0xFFFFFF) * 32 + fl];
                uint v3 = h1u[(size_t)(e3.x & 0xFFFFFF) * 32 + fl];
                float w0 = __int_as_float(e0.y), w1 = __int_as_float(e1.y);
                float w2 = __int_as_float(e2.y), w3 = __int_as_float(e3.y);
                ax += __uint_as_float(v0 << 16) * w0 + __uint_as_float(v1 << 16) * w1
                    + __uint_as_float(v2 << 16) * w2 + __uint_as_float(v3 << 16) * w3;
                ay += __uint_as_float(v0 & 0xFFFF0000u) * w0 + __uint_as_float(v1 & 0xFFFF0000u) * w1
                    + __uint_as_float(v2 & 0xFFFF0000u) * w2 + __uint_as_float(v3 & 0xFFFF0000u) * w3;
            }
            for (; p < pend; p += 2) {
                if (p + h < pend) {
                    int2 e = es[p + h];
                    uint v = h1u[(size_t)(e.x & 0xFFFFFF) * 32 + fl];
                    float w = __int_as_float(e.y);
                    ax += __uint_as_float(v << 16) * w;
                    ay += __uint_as_float(v & 0xFFFF0000u) * w;
                }
            }
            ax += __shfl_xor(ax, 32, 64);
            ay += __shfl_xor(ay, 32, 64);
        }
        if (h == 0) {   // write bf16 t-row (packed uint store)
            uint tx = (uint)f2bf(fmaxf(ax + b1s[2*fl],     0.f));
            uint ty = (uint)f2bf(fmaxf(ay + b1s[2*fl + 1], 0.f));
            tsu[(wave*16 + i) * 36 + fl] = tx | (ty << 16);
        }
    }
    // layer2 MFMA on this wave's own 16 rows (intra-wave LDS dep, in-order)
    const int m = lane & 15, quad = lane >> 4;
    floatx4 acc[2] = {(floatx4)(0.f), (floatx4)(0.f)};
    #pragma unroll
    for (int step = 0; step < 2; step++) {
        short8 a = *(const short8*)&ts[wave*16 + m][step*32 + quad*8];
        #pragma unroll
        for (int nt = 0; nt < 2; nt++) {
            short8 b = *(const short8*)&wf2[nt][step][lane][0];
            acc[nt] = __builtin_amdgcn_mfma_f32_16x16x32_bf16(a, b, acc[nt], 0, 0, 0);
        }
    }
    #pragma unroll
    for (int nt = 0; nt < 2; nt++) {
        #pragma unroll
        for (int r = 0; r < 4; r++) {
            int g = node0 + quad*4 + r;
            if (g < N) h2[(size_t)g*32 + nt*16 + m] = f2bf(acc[nt][r]);
        }
    }
}

// ------- gather2: wave/node, 16 lanes/edge (2 feats/lane), out f32 -------
__global__ __launch_bounds__(256) void gather2_kernel(
    const u16* __restrict__ h2, const int2* __restrict__ es,
    const int* __restrict__ off, const float* __restrict__ b2,
    float* __restrict__ out, int N)
{
    const int tid = threadIdx.x;
    const int wave = tid >> 6, lane = tid & 63;
    const int d = blockIdx.x * 4 + wave;
    if (d >= N) return;
    const int q = lane >> 4, fl = lane & 15;

    int pbeg = __builtin_amdgcn_readfirstlane(off[d]);
    int pend = __builtin_amdgcn_readfirstlane(off[d + 1]);

    const uint* h2u = (const uint*)h2;     // h2 row = 16 uints (32 bf16)
    float ax = 0.f, ay = 0.f;
    int p = pbeg;
    for (; p + 8 <= pend; p += 8) {        // 8 edges/iter, 2 gathers/lane
        int2 ea = es[p + q], eb = es[p + 4 + q];
        uint va = h2u[(size_t)(ea.x & 0xFFFFFF) * 16 + fl];
        uint vb = h2u[(size_t)(eb.x & 0xFFFFFF) * 16 + fl];
        float wa = __int_as_float(ea.y), wb = __int_as_float(eb.y);
        ax += __uint_as_float(va << 16) * wa + __uint_as_float(vb << 16) * wb;
        ay += __uint_as_float(va & 0xFFFF0000u) * wa + __uint_as_float(vb & 0xFFFF0000u) * wb;
    }
    for (; p < pend; p += 4) {
        if (p + q < pend) {
            int2 e = es[p + q];
            uint v = h2u[(size_t)(e.x & 0xFFFFFF) * 16 + fl];
            float w = __int_as_float(e.y);
            ax += __uint_as_float(v << 16) * w;
            ay += __uint_as_float(v & 0xFFFF0000u) * w;
        }
    }
    ax += __shfl_xor(ax, 16, 64); ay += __shfl_xor(ay, 16, 64);
    ax += __shfl_xor(ax, 32, 64); ay += __shfl_xor(ay, 32, 64);
    if (q == 0) {
        float2 bb = *(const float2*)&b2[2 * fl];
        *(float2*)&out[(size_t)d * 32 + 2 * fl] = make_float2(ax + bb.x, ay + bb.y);
    }
}

extern "C" void kernel_launch(void* const* d_in, const int* in_sizes, int n_in,
                              void* d_out, int out_size, void* d_ws, size_t ws_size,
                              hipStream_t stream)
{
    const float* x   = (const float*)d_in[0];
    const int*  esrc = (const int*)d_in[1];
    const int*  edst = (const int*)d_in[2];
    const float* ew  = (const float*)d_in[3];
    const float* W1  = (const float*)d_in[4];
    const float* b1  = (const float*)d_in[5];
    const float* W2  = (const float*)d_in[6];
    const float* b2  = (const float*)d_in[7];
    float* out = (float*)d_out;

    const int N = in_sizes[0] / 128;   // 100000
    const int E = in_sizes[1];         // 1600000
    const int nb = (N + 255) >> 8;     // 391 buckets
    const int B = (N + 255) / 256;     // scan blocks (391)

    char* base = (char*)d_ws;
    size_t o = 0;
    auto alloc = [&](size_t bytes) { char* p = base + o; o = (o + bytes + 255) & ~(size_t)255; return p; };
    u16*  h1           = (u16*) alloc((size_t)N * 64 * 2);
    u16*  h2           = (u16*) alloc((size_t)N * 32 * 2);
    int2* es           = (int2*)alloc((size_t)E * 8);
    int2* es2          = (int2*)alloc((size_t)E * 8);
    int*  off          = (int*) alloc((size_t)(N + 1) * 4);
    int*  counts       = (int*) alloc((size_t)N * 4);
    int*  gcursor      = (int*) alloc(512 * 4);
    int*  partials     = (int*) alloc(1024 * 4);
    int*  partials_off = (int*) alloc(1024 * 4);

    hipMemsetAsync(counts, 0, (size_t)N * 4, stream);
    g1_mfma<<<(N + 63) / 64, 256, 0, stream>>>(x, W1, h1, N);
    hist_kernel<<<(E + 255) / 256, 256, 0, stream>>>(edst, counts, E);
    scan_partial_kernel<<<B, 256, 0, stream>>>(counts, partials, N);
    scan_top_kernel<<<1, 1024, 0, stream>>>(partials, partials_off, B);
    scan_final_kernel<<<B, 256, 0, stream>>>(counts, partials_off, off, gcursor, N);
    partition_kernel<<<(E + CHUNK - 1) / CHUNK, 512, 0, stream>>>(esrc, edst, ew, gcursor, es, E);
    sort2_kernel<<<nb, 512, 0, stream>>>(es, off, es2, N);
    gather1_kernel<<<(N + 63) / 64, 256, 0, stream>>>(h1, es2, off, b1, W2, h2, N);
    gather2_kernel<<<(N + 3) / 4, 256, 0, stream>>>(h2, es2, off, b2, out, N);
}

// Round 8
// 288.429 us; speedup vs baseline: 1.1215x; 1.1215x over previous
//
#include <hip/hip_runtime.h>
#include <hip/hip_bf16.h>

// GCN 2-layer, two-pass dst-radix-sort + batched wave gathers:
//   h1 = bf16( bf16(x) @ bf16(W1) )     (MFMA 16x16x32, [N,64])
//   bucket_hist (LDS-preagg) -> bucket_scan -> boff/gcursor   [512 buckets]
//   pass1: partition edges into buckets of 256 dst (dst>>8), LDS-staged runs
//   pass2: per-bucket counting sort by dst&255 -> es2 (dst-sorted) + off[]
//   gather1 (batched): wave gathers 16 nodes -> LDS bf16 tile; layer2 via MFMA
//   gather2 (wave/node, 16 lanes/edge): out = segsum(h2[src]*w) + b2 (f32)

typedef unsigned short u16;
typedef unsigned int uint;
typedef short short8 __attribute__((ext_vector_type(8)));
typedef float floatx4 __attribute__((ext_vector_type(4)));

static __device__ __forceinline__ float bf2f(u16 v) {
    return __uint_as_float(((unsigned int)v) << 16);
}
static __device__ __forceinline__ u16 f2bf(float f) {
    unsigned int u = __float_as_uint(f);
    return (u16)((u + 0x7fff + ((u >> 16) & 1)) >> 16);   // RNE
}

#define F4C(v, j) ((j)==0?(v).x:((j)==1?(v).y:((j)==2?(v).z:(v).w)))

// ---------------- g1_mfma: h1 = x @ W1 via bf16 MFMA ----------------
__global__ __launch_bounds__(256, 4) void g1_mfma(
    const float* __restrict__ x, const float* __restrict__ W1,
    u16* __restrict__ h1, int N)
{
    __shared__ __align__(16) u16 xs[64][136];
    __shared__ __align__(16) u16 wf[4][4][64][8];      // [ntile][step][lane][j]
    const int tid  = threadIdx.x;
    const int row0 = blockIdx.x * 64;

    {   // stage W1 (128x64 f32) -> bf16, swizzled to B-fragment order
        const float4* W4 = (const float4*)W1;
        #pragma unroll
        for (int i = 0; i < 8; i++) {
            int idx = tid + i*256;
            int k = idx >> 4, n4 = (idx & 15) * 4;
            float4 v = W4[idx];
            int step = k >> 5, klane = (k >> 3) & 3, j = k & 7;
            #pragma unroll
            for (int c = 0; c < 4; c++) {
                int n = n4 + c;
                wf[n >> 4][step][klane*16 + (n & 15)][j] = f2bf(F4C(v, c));
            }
        }
    }
    {   // stage x tile -> bf16
        const float4* x4 = (const float4*)x;
        #pragma unroll
        for (int i = 0; i < 8; i++) {
            int idx = tid + i*256;
            int r = idx >> 5, kc = idx & 31;
            int gr = row0 + r;
            float4 v = make_float4(0.f,0.f,0.f,0.f);
            if (gr < N) v = x4[gr*32 + kc];
            ushort4 o;
            o.x = f2bf(v.x); o.y = f2bf(v.y); o.z = f2bf(v.z); o.w = f2bf(v.w);
            *(ushort4*)&xs[r][kc*4] = o;
        }
    }
    __syncthreads();

    const int wave = tid >> 6, lane = tid & 63;
    const int m = lane & 15, quad = lane >> 4;
    const int rw = wave * 16;

    floatx4 acc[4] = {(floatx4)(0.f), (floatx4)(0.f), (floatx4)(0.f), (floatx4)(0.f)};
    #pragma unroll
    for (int step = 0; step < 4; step++) {
        short8 a = *(const short8*)&xs[rw + m][step*32 + quad*8];
        #pragma unroll
        for (int nt = 0; nt < 4; nt++) {
            short8 b = *(const short8*)&wf[nt][step][lane][0];
            acc[nt] = __builtin_amdgcn_mfma_f32_16x16x32_bf16(a, b, acc[nt], 0, 0, 0);
        }
    }
    #pragma unroll
    for (int nt = 0; nt < 4; nt++) {
        #pragma unroll
        for (int r = 0; r < 4; r++) {
            int gr = row0 + rw + quad*4 + r;
            if (gr < N) h1[(size_t)gr*64 + nt*16 + m] = f2bf(acc[nt][r]);
        }
    }
}

// ---------------- bucket histogram (LDS pre-aggregated) ----------------
__global__ __launch_bounds__(256) void bucket_hist(
    const int* __restrict__ dst, int* __restrict__ counts, int E)
{
    __shared__ int h[512];
    const int tid = threadIdx.x;
    for (int i = tid; i < 512; i += 256) h[i] = 0;
    __syncthreads();
    int base = blockIdx.x * 1024;
    #pragma unroll
    for (int k = 0; k < 4; k++) {
        int i = base + k*256 + tid;
        if (i < E) atomicAdd(&h[dst[i] >> 8], 1);
    }
    __syncthreads();
    for (int i = tid; i < 512; i += 256)
        if (h[i]) atomicAdd(&counts[i], h[i]);
}

// ---------------- bucket scan (1 block, 512 threads) ----------------
__global__ __launch_bounds__(512) void bucket_scan(
    const int* __restrict__ counts, int* __restrict__ boff,
    int* __restrict__ gcursor, int nb)
{
    __shared__ int A[512], B[512];
    const int t = threadIdx.x;
    int v = (t < nb) ? counts[t] : 0;
    A[t] = v;
    __syncthreads();
    int* cur = A; int* nxt = B;
    for (int off = 1; off < 512; off <<= 1) {
        nxt[t] = cur[t] + ((t >= off) ? cur[t - off] : 0);
        __syncthreads();
        int* tmp = cur; cur = nxt; nxt = tmp;
    }
    int ex = cur[t] - v;           // exclusive
    if (t <= nb) boff[t] = ex;     // boff[nb] == E
    if (t < nb)  gcursor[t] = ex;
}

// ---------------- pass1: LDS-staged scatter into bucket runs ----------
// entry: x = src | (dst&255)<<24 ; y = w bits
#define CHUNK 4096
#define PT 512
__global__ __launch_bounds__(512, 2) void partition_kernel(
    const int* __restrict__ src, const int* __restrict__ dst,
    const float* __restrict__ w, int* __restrict__ gcursor,
    int2* __restrict__ es, int E)
{
    __shared__ int2 stage[CHUNK];        // 32 KB
    __shared__ u16  stb[CHUNK];          // 8 KB
    __shared__ int  hist[512];
    __shared__ int  sc[512];
    __shared__ int  xscan[512], place[512], runbase[512];
    const int tid = threadIdx.x;
    const int base = blockIdx.x * CHUNK;
    const int nloc = min(CHUNK, E - base);

    hist[tid] = 0;
    __syncthreads();
    for (int i = tid; i < nloc; i += PT)
        atomicAdd(&hist[dst[base + i] >> 8], 1);
    __syncthreads();

    int v = hist[tid];
    sc[tid] = v;
    __syncthreads();
    for (int o = 1; o < 512; o <<= 1) {          // Hillis-Steele inclusive
        int add = (tid >= o) ? sc[tid - o] : 0;
        __syncthreads();
        sc[tid] += add;
        __syncthreads();
    }
    int ex = sc[tid] - v;
    xscan[tid] = ex;
    place[tid] = ex;
    __syncthreads();

    for (int i = tid; i < nloc; i += PT) {
        int d = dst[base + i];
        int b = d >> 8;
        int pos = atomicAdd(&place[b], 1);
        stage[pos] = make_int2(src[base + i] | ((d & 255) << 24),
                               __float_as_int(w[base + i]));
        stb[pos] = (u16)b;
    }
    __syncthreads();

    runbase[tid] = hist[tid] ? atomicAdd(&gcursor[tid], hist[tid]) : 0;
    __syncthreads();

    for (int i = tid; i < nloc; i += PT) {
        int b = stb[i];
        es[runbase[b] + (i - xscan[b])] = stage[i];
    }
}

// ------- pass2: per-bucket counting sort by dst&255 -> es2 + off[] -------
__global__ __launch_bounds__(512) void sort2_kernel(
    const int2* __restrict__ es, const int* __restrict__ boff,
    int2* __restrict__ es2, int* __restrict__ off, int N, int nb)
{
    __shared__ int hist[256], sc[256], cur[256];
    const int t = threadIdx.x;
    const int b = blockIdx.x;
    const int e0 = boff[b], e1 = boff[b + 1];

    if (t < 256) hist[t] = 0;
    __syncthreads();
    for (int i = e0 + t; i < e1; i += 512)
        atomicAdd(&hist[((unsigned)es[i].x) >> 24], 1);
    __syncthreads();

    int v = 0;
    if (t < 256) { v = hist[t]; sc[t] = v; }
    __syncthreads();
    for (int o = 1; o < 256; o <<= 1) {
        int add = 0;
        if (t < 256 && t >= o) add = sc[t - o];
        __syncthreads();
        if (t < 256) sc[t] += add;
        __syncthreads();
    }
    if (t < 256) {
        int ex = sc[t] - v;                  // exclusive within bucket
        cur[t] = ex;
        int g = b * 256 + t;
        if (g < N) off[g] = e0 + ex;
        if (b == nb - 1 && t == 0) off[N] = e1;   // == E
    }
    __syncthreads();

    for (int i = e0 + t; i < e1; i += 512) {
        int2 e = es[i];
        int pos = e0 + atomicAdd(&cur[((unsigned)e.x) >> 24], 1);
        es2[pos] = e;                        // scatter within 32 KB window
    }
}

// ------- gather1 batched: 64 nodes/block, wave gathers 16 nodes -> LDS bf16
//         then layer2 (relu(+b1) @ W2) via MFMA on the wave's own 16 rows ----
__global__ __launch_bounds__(256) void gather1_kernel(
    const u16* __restrict__ h1, const int2* __restrict__ es,
    const int* __restrict__ off, const float* __restrict__ b1,
    const float* __restrict__ W2, u16* __restrict__ h2, int N)
{
    __shared__ __align__(16) u16 ts[64][72];          // t rows, bf16 (144B rows)
    __shared__ __align__(16) u16 wf2[2][2][64][8];    // [ntile][step][lane][j]
    __shared__ float b1s[64];
    const int tid = threadIdx.x;

    {   // stage W2 (64x32 f32 = 512 float4) -> bf16 B-fragments, + b1
        const float4* s4 = (const float4*)W2;
        #pragma unroll
        for (int i = 0; i < 2; i++) {
            int idx = tid + i*256;
            float4 v = s4[idx];
            int k = idx >> 3, n4 = (idx & 7) * 4;
            int step = k >> 5, quad = (k >> 3) & 3, j = k & 7;
            #pragma unroll
            for (int c = 0; c < 4; c++) {
                int n = n4 + c;
                wf2[n >> 4][step][quad*16 + (n & 15)][j] = f2bf(F4C(v, c));
            }
        }
        if (tid < 16) ((float4*)b1s)[tid] = ((const float4*)b1)[tid];
    }
    __syncthreads();

    const int wave = tid >> 6, lane = tid & 63;
    const int h = lane >> 5, fl = lane & 31;
    const int node0 = blockIdx.x * 64 + wave * 16;
    const uint* h1u = (const uint*)h1;     // h1 row = 32 uints (64 bf16)
    uint* tsu = (uint*)&ts[0][0];          // rows of 36 uints

    #pragma unroll 1
    for (int i = 0; i < 16; i++) {
        const int d = node0 + i;
        float ax = 0.f, ay = 0.f;
        if (d < N) {                       // wave-uniform branch
            int pbeg = __builtin_amdgcn_readfirstlane(off[d]);
            int pend = __builtin_amdgcn_readfirstlane(off[d + 1]);
            int p = pbeg;
            for (; p + 8 <= pend; p += 8) {    // 8 edges/iter, 4 gathers in flight
                int2 e0 = es[p + h],     e1 = es[p + 2 + h];
                int2 e2 = es[p + 4 + h], e3 = es[p + 6 + h];
                uint v0 = h1u[(size_t)(e0.x & 0xFFFFFF) * 32 + fl];
                uint v1 = h1u[(size_t)(e1.x & 0xFFFFFF) * 32 + fl];
                uint v2 = h1u[(size_t)(e2.x & 0xFFFFFF) * 32 + fl];
                uint v3 = h1u[(size_t)(e3.x & 0xFFFFFF) * 32 + fl];
                float w0 = __int_as_float(e0.y), w1 = __int_as_float(e1.y);
                float w2 = __int_as_float(e2.y), w3 = __int_as_float(e3.y);
                ax += __uint_as_float(v0 << 16) * w0 + __uint_as_float(v1 << 16) * w1
                    + __uint_as_float(v2 << 16) * w2 + __uint_as_float(v3 << 16) * w3;
                ay += __uint_as_float(v0 & 0xFFFF0000u) * w0 + __uint_as_float(v1 & 0xFFFF0000u) * w1
                    + __uint_as_float(v2 & 0xFFFF0000u) * w2 + __uint_as_float(v3 & 0xFFFF0000u) * w3;
            }
            for (; p < pend; p += 2) {
                if (p + h < pend) {
                    int2 e = es[p + h];
                    uint v = h1u[(size_t)(e.x & 0xFFFFFF) * 32 + fl];
                    float w = __int_as_float(e.y);
                    ax += __uint_as_float(v << 16) * w;
                    ay += __uint_as_float(v & 0xFFFF0000u) * w;
                }
            }
            ax += __shfl_xor(ax, 32, 64);
            ay += __shfl_xor(ay, 32, 64);
        }
        if (h == 0) {   // write bf16 t-row (packed uint store)
            uint tx = (uint)f2bf(fmaxf(ax + b1s[2*fl],     0.f));
            uint ty = (uint)f2bf(fmaxf(ay + b1s[2*fl + 1], 0.f));
            tsu[(wave*16 + i) * 36 + fl] = tx | (ty << 16);
        }
    }
    // layer2 MFMA on this wave's own 16 rows (intra-wave LDS dep, in-order)
    const int m = lane & 15, quad = lane >> 4;
    floatx4 acc[2] = {(floatx4)(0.f), (floatx4)(0.f)};
    #pragma unroll
    for (int step = 0; step < 2; step++) {
        short8 a = *(const short8*)&ts[wave*16 + m][step*32 + quad*8];
        #pragma unroll
        for (int nt = 0; nt < 2; nt++) {
            short8 b = *(const short8*)&wf2[nt][step][lane][0];
            acc[nt] = __builtin_amdgcn_mfma_f32_16x16x32_bf16(a, b, acc[nt], 0, 0, 0);
        }
    }
    #pragma unroll
    for (int nt = 0; nt < 2; nt++) {
        #pragma unroll
        for (int r = 0; r < 4; r++) {
            int g = node0 + quad*4 + r;
            if (g < N) h2[(size_t)g*32 + nt*16 + m] = f2bf(acc[nt][r]);
        }
    }
}

// ------- gather2: wave/node, 16 lanes/edge (2 feats/lane), out f32 -------
__global__ __launch_bounds__(256) void gather2_kernel(
    const u16* __restrict__ h2, const int2* __restrict__ es,
    const int* __restrict__ off, const float* __restrict__ b2,
    float* __restrict__ out, int N)
{
    const int tid = threadIdx.x;
    const int wave = tid >> 6, lane = tid & 63;
    const int d = blockIdx.x * 4 + wave;
    if (d >= N) return;
    const int q = lane >> 4, fl = lane & 15;

    int pbeg = __builtin_amdgcn_readfirstlane(off[d]);
    int pend = __builtin_amdgcn_readfirstlane(off[d + 1]);

    const uint* h2u = (const uint*)h2;     // h2 row = 16 uints (32 bf16)
    float ax = 0.f, ay = 0.f;
    int p = pbeg;
    for (; p + 8 <= pend; p += 8) {        // 8 edges/iter, 2 gathers/lane
        int2 ea = es[p + q], eb = es[p + 4 + q];
        uint va = h2u[(size_t)(ea.x & 0xFFFFFF) * 16 + fl];
        uint vb = h2u[(size_t)(eb.x & 0xFFFFFF) * 16 + fl];
        float wa = __int_as_float(ea.y), wb = __int_as_float(eb.y);
        ax += __uint_as_float(va << 16) * wa + __uint_as_float(vb << 16) * wb;
        ay += __uint_as_float(va & 0xFFFF0000u) * wa + __uint_as_float(vb & 0xFFFF0000u) * wb;
    }
    for (; p < pend; p += 4) {
        if (p + q < pend) {
            int2 e = es[p + q];
            uint v = h2u[(size_t)(e.x & 0xFFFFFF) * 16 + fl];
            float w = __int_as_float(e.y);
            ax += __uint_as_float(v << 16) * w;
            ay += __uint_as_float(v & 0xFFFF0000u) * w;
        }
    }
    ax += __shfl_xor(ax, 16, 64); ay += __shfl_xor(ay, 16, 64);
    ax += __shfl_xor(ax, 32, 64); ay += __shfl_xor(ay, 32, 64);
    if (q == 0) {
        float2 bb = *(const float2*)&b2[2 * fl];
        *(float2*)&out[(size_t)d * 32 + 2 * fl] = make_float2(ax + bb.x, ay + bb.y);
    }
}

extern "C" void kernel_launch(void* const* d_in, const int* in_sizes, int n_in,
                              void* d_out, int out_size, void* d_ws, size_t ws_size,
                              hipStream_t stream)
{
    const float* x   = (const float*)d_in[0];
    const int*  esrc = (const int*)d_in[1];
    const int*  edst = (const int*)d_in[2];
    const float* ew  = (const float*)d_in[3];
    const float* W1  = (const float*)d_in[4];
    const float* b1  = (const float*)d_in[5];
    const float* W2  = (const float*)d_in[6];
    const float* b2  = (const float*)d_in[7];
    float* out = (float*)d_out;

    const int N = in_sizes[0] / 128;   // 100000
    const int E = in_sizes[1];         // 1600000
    const int nb = (N + 255) >> 8;     // 391 buckets

    char* base = (char*)d_ws;
    size_t o = 0;
    auto alloc = [&](size_t bytes) { char* p = base + o; o = (o + bytes + 255) & ~(size_t)255; return p; };
    u16*  h1      = (u16*) alloc((size_t)N * 64 * 2);
    u16*  h2      = (u16*) alloc((size_t)N * 32 * 2);
    int2* es      = (int2*)alloc((size_t)E * 8);
    int2* es2     = (int2*)alloc((size_t)E * 8);
    int*  off     = (int*) alloc((size_t)(N + 1) * 4);
    int*  counts  = (int*) alloc(512 * 4);
    int*  boff    = (int*) alloc(512 * 4);
    int*  gcursor = (int*) alloc(512 * 4);

    hipMemsetAsync(counts, 0, 512 * 4, stream);
    g1_mfma<<<(N + 63) / 64, 256, 0, stream>>>(x, W1, h1, N);
    bucket_hist<<<(E + 1023) / 1024, 256, 0, stream>>>(edst, counts, E);
    bucket_scan<<<1, 512, 0, stream>>>(counts, boff, gcursor, nb);
    partition_kernel<<<(E + CHUNK - 1) / CHUNK, 512, 0, stream>>>(esrc, edst, ew, gcursor, es, E);
    sort2_kernel<<<nb, 512, 0, stream>>>(es, boff, es2, off, N, nb);
    gather1_kernel<<<(N + 63) / 64, 256, 0, stream>>>(h1, es2, off, b1, W2, h2, N);
    gather2_kernel<<<(N + 3) / 4, 256, 0, stream>>>(h2, es2, off, b2, out, N);
}

// Round 9
// 268.676 us; speedup vs baseline: 1.2039x; 1.0735x over previous
//
#include <hip/hip_runtime.h>
#include <hip/hip_bf16.h>

// GCN 2-layer, two-pass dst-radix-sort + batched wave gathers:
//   h1 = bf16( bf16(x) @ bf16(W1) )  (MFMA 16x16x32) -- fused with bucket_hist
//   bucket_scan -> boff/gcursor   [512 buckets of 256 dst]
//   pass1: partition edges into buckets (dst>>8), LDS-staged runs
//   pass2: single-pass per-bucket counting sort by dst&255 (LDS-staged) -> es2+off
//   gather1 (batched, offset-prefetch): wave gathers 16 nodes; layer2 via MFMA
//   gather2 (batched, offset-prefetch): out = segsum(h2[src]*w) + b2 (f32)

typedef unsigned short u16;
typedef unsigned int uint;
typedef short short8 __attribute__((ext_vector_type(8)));
typedef float floatx4 __attribute__((ext_vector_type(4)));

static __device__ __forceinline__ float bf2f(u16 v) {
    return __uint_as_float(((unsigned int)v) << 16);
}
static __device__ __forceinline__ u16 f2bf(float f) {
    unsigned int u = __float_as_uint(f);
    return (u16)((u + 0x7fff + ((u >> 16) & 1)) >> 16);   // RNE
}

#define F4C(v, j) ((j)==0?(v).x:((j)==1?(v).y:((j)==2?(v).z:(v).w)))

// ------- g1h: blocks [0,gblocks) do h1 = x@W1 (MFMA); tail blocks do bucket hist
__global__ __launch_bounds__(256, 4) void g1h_kernel(
    const float* __restrict__ x, const float* __restrict__ W1,
    u16* __restrict__ h1, int N,
    const int* __restrict__ dst, int* __restrict__ counts, int E, int gblocks)
{
    __shared__ __align__(16) u16 xs[64][136];
    __shared__ __align__(16) u16 wf[4][4][64][8];      // [ntile][step][lane][j]
    __shared__ int hh[512];
    const int tid = threadIdx.x;

    if (blockIdx.x >= gblocks) {           // ---- bucket histogram part ----
        const int bid = blockIdx.x - gblocks;
        for (int i = tid; i < 512; i += 256) hh[i] = 0;
        __syncthreads();
        int base = bid * 1024;
        #pragma unroll
        for (int k = 0; k < 4; k++) {
            int i = base + k*256 + tid;
            if (i < E) atomicAdd(&hh[dst[i] >> 8], 1);
        }
        __syncthreads();
        for (int i = tid; i < 512; i += 256)
            if (hh[i]) atomicAdd(&counts[i], hh[i]);
        return;
    }

    // ---- GEMM part ----
    const int row0 = blockIdx.x * 64;
    {   // stage W1 (128x64 f32) -> bf16, swizzled to B-fragment order
        const float4* W4 = (const float4*)W1;
        #pragma unroll
        for (int i = 0; i < 8; i++) {
            int idx = tid + i*256;
            int k = idx >> 4, n4 = (idx & 15) * 4;
            float4 v = W4[idx];
            int step = k >> 5, klane = (k >> 3) & 3, j = k & 7;
            #pragma unroll
            for (int c = 0; c < 4; c++) {
                int n = n4 + c;
                wf[n >> 4][step][klane*16 + (n & 15)][j] = f2bf(F4C(v, c));
            }
        }
    }
    {   // stage x tile -> bf16
        const float4* x4 = (const float4*)x;
        #pragma unroll
        for (int i = 0; i < 8; i++) {
            int idx = tid + i*256;
            int r = idx >> 5, kc = idx & 31;
            int gr = row0 + r;
            float4 v = make_float4(0.f,0.f,0.f,0.f);
            if (gr < N) v = x4[gr*32 + kc];
            ushort4 o;
            o.x = f2bf(v.x); o.y = f2bf(v.y); o.z = f2bf(v.z); o.w = f2bf(v.w);
            *(ushort4*)&xs[r][kc*4] = o;
        }
    }
    __syncthreads();

    const int wave = tid >> 6, lane = tid & 63;
    const int m = lane & 15, quad = lane >> 4;
    const int rw = wave * 16;

    floatx4 acc[4] = {(floatx4)(0.f), (floatx4)(0.f), (floatx4)(0.f), (floatx4)(0.f)};
    #pragma unroll
    for (int step = 0; step < 4; step++) {
        short8 a = *(const short8*)&xs[rw + m][step*32 + quad*8];
        #pragma unroll
        for (int nt = 0; nt < 4; nt++) {
            short8 b = *(const short8*)&wf[nt][step][lane][0];
            acc[nt] = __builtin_amdgcn_mfma_f32_16x16x32_bf16(a, b, acc[nt], 0, 0, 0);
        }
    }
    #pragma unroll
    for (int nt = 0; nt < 4; nt++) {
        #pragma unroll
        for (int r = 0; r < 4; r++) {
            int gr = row0 + rw + quad*4 + r;
            if (gr < N) h1[(size_t)gr*64 + nt*16 + m] = f2bf(acc[nt][r]);
        }
    }
}

// ---------------- bucket scan (1 block, 512 threads) ----------------
__global__ __launch_bounds__(512) void bucket_scan(
    const int* __restrict__ counts, int* __restrict__ boff,
    int* __restrict__ gcursor, int nb)
{
    __shared__ int A[512], B[512];
    const int t = threadIdx.x;
    int v = (t < nb) ? counts[t] : 0;
    A[t] = v;
    __syncthreads();
    int* cur = A; int* nxt = B;
    for (int off = 1; off < 512; off <<= 1) {
        nxt[t] = cur[t] + ((t >= off) ? cur[t - off] : 0);
        __syncthreads();
        int* tmp = cur; cur = nxt; nxt = tmp;
    }
    int ex = cur[t] - v;           // exclusive
    if (t <= nb) boff[t] = ex;     // boff[nb] == E
    if (t < nb)  gcursor[t] = ex;
}

// ---------------- pass1: LDS-staged scatter into bucket runs ----------
// entry: x = src | (dst&255)<<24 ; y = w bits
#define CHUNK 4096
#define PT 512
__global__ __launch_bounds__(512, 2) void partition_kernel(
    const int* __restrict__ src, const int* __restrict__ dst,
    const float* __restrict__ w, int* __restrict__ gcursor,
    int2* __restrict__ es, int E)
{
    __shared__ int2 stage[CHUNK];        // 32 KB
    __shared__ u16  stb[CHUNK];          // 8 KB
    __shared__ int  hist[512];
    __shared__ int  sc[512];
    __shared__ int  xscan[512], place[512], runbase[512];
    const int tid = threadIdx.x;
    const int base = blockIdx.x * CHUNK;
    const int nloc = min(CHUNK, E - base);

    hist[tid] = 0;
    __syncthreads();
    for (int i = tid; i < nloc; i += PT)
        atomicAdd(&hist[dst[base + i] >> 8], 1);
    __syncthreads();

    int v = hist[tid];
    sc[tid] = v;
    __syncthreads();
    for (int o = 1; o < 512; o <<= 1) {          // Hillis-Steele inclusive
        int add = (tid >= o) ? sc[tid - o] : 0;
        __syncthreads();
        sc[tid] += add;
        __syncthreads();
    }
    int ex = sc[tid] - v;
    xscan[tid] = ex;
    place[tid] = ex;
    __syncthreads();

    for (int i = tid; i < nloc; i += PT) {
        int d = dst[base + i];
        int b = d >> 8;
        int pos = atomicAdd(&place[b], 1);
        stage[pos] = make_int2(src[base + i] | ((d & 255) << 24),
                               __float_as_int(w[base + i]));
        stb[pos] = (u16)b;
    }
    __syncthreads();

    runbase[tid] = hist[tid] ? atomicAdd(&gcursor[tid], hist[tid]) : 0;
    __syncthreads();

    for (int i = tid; i < nloc; i += PT) {
        int b = stb[i];
        es[runbase[b] + (i - xscan[b])] = stage[i];
    }
}

// ------- pass2: per-bucket single-pass counting sort (LDS-staged) -------
#define SCAP 6144
__global__ __launch_bounds__(512, 3) void sort2_kernel(
    const int2* __restrict__ es, const int* __restrict__ boff,
    int2* __restrict__ es2, int* __restrict__ off, int N, int nb)
{
    __shared__ int2 stage[SCAP];                  // 48 KB
    __shared__ int hist[256], sc[256], cur[256];
    const int t = threadIdx.x;
    const int b = blockIdx.x;
    const int e0 = boff[b], e1 = boff[b + 1];
    const int len = e1 - e0;
    const int nstage = min(len, SCAP);

    if (t < 256) hist[t] = 0;
    __syncthreads();
    for (int i = t; i < nstage; i += 512) {       // stage + hist in one pass
        int2 e = es[e0 + i];
        stage[i] = e;
        atomicAdd(&hist[((unsigned)e.x) >> 24], 1);
    }
    for (int i = SCAP + t; i < len; i += 512)     // overflow: hist from global
        atomicAdd(&hist[((unsigned)es[e0 + i].x) >> 24], 1);
    __syncthreads();

    int v = 0;
    if (t < 256) { v = hist[t]; sc[t] = v; }
    __syncthreads();
    for (int o = 1; o < 256; o <<= 1) {
        int add = 0;
        if (t < 256 && t >= o) add = sc[t - o];
        __syncthreads();
        if (t < 256) sc[t] += add;
        __syncthreads();
    }
    if (t < 256) {
        int ex = sc[t] - v;                       // exclusive within bucket
        cur[t] = ex;
        int g = b * 256 + t;
        if (g < N) off[g] = e0 + ex;
        if (b == nb - 1 && t == 0) off[N] = e1;   // == E
    }
    __syncthreads();

    for (int i = t; i < nstage; i += 512) {
        int2 e = stage[i];
        int pos = e0 + atomicAdd(&cur[((unsigned)e.x) >> 24], 1);
        es2[pos] = e;                             // scatter within 32 KB window
    }
    for (int i = SCAP + t; i < len; i += 512) {   // overflow scatter
        int2 e = es[e0 + i];
        int pos = e0 + atomicAdd(&cur[((unsigned)e.x) >> 24], 1);
        es2[pos] = e;
    }
}

// ------- gather1 batched: 64 nodes/block, wave gathers 16 nodes -> LDS bf16
//         offsets prefetched; layer2 (relu(+b1) @ W2) via MFMA ----
__global__ __launch_bounds__(256) void gather1_kernel(
    const u16* __restrict__ h1, const int2* __restrict__ es,
    const int* __restrict__ off, const float* __restrict__ b1,
    const float* __restrict__ W2, u16* __restrict__ h2, int N)
{
    __shared__ __align__(16) u16 ts[64][72];          // t rows, bf16 (144B rows)
    __shared__ __align__(16) u16 wf2[2][2][64][8];    // [ntile][step][lane][j]
    __shared__ float b1s[64];
    const int tid = threadIdx.x;

    {   // stage W2 (64x32 f32 = 512 float4) -> bf16 B-fragments, + b1
        const float4* s4 = (const float4*)W2;
        #pragma unroll
        for (int i = 0; i < 2; i++) {
            int idx = tid + i*256;
            float4 v = s4[idx];
            int k = idx >> 3, n4 = (idx & 7) * 4;
            int step = k >> 5, quad = (k >> 3) & 3, j = k & 7;
            #pragma unroll
            for (int c = 0; c < 4; c++) {
                int n = n4 + c;
                wf2[n >> 4][step][quad*16 + (n & 15)][j] = f2bf(F4C(v, c));
            }
        }
        if (tid < 16) ((float4*)b1s)[tid] = ((const float4*)b1)[tid];
    }
    __syncthreads();

    const int wave = tid >> 6, lane = tid & 63;
    const int h = lane >> 5, fl = lane & 31;
    const int node0 = blockIdx.x * 64 + wave * 16;
    const uint* h1u = (const uint*)h1;     // h1 row = 32 uints (64 bf16)
    uint* tsu = (uint*)&ts[0][0];          // rows of 36 uints

    // prefetch this wave's 17 segment offsets (lanes 0..16)
    const int segoff = off[min(node0 + min(lane, 16), N)];

    #pragma unroll 1
    for (int i = 0; i < 16; i++) {
        const int pbeg = __builtin_amdgcn_readlane(segoff, i);
        const int pend = __builtin_amdgcn_readlane(segoff, i + 1);
        float ax = 0.f, ay = 0.f;
        int p = pbeg;
        for (; p + 8 <= pend; p += 8) {    // 8 edges/iter, 4 gathers in flight
            int2 e0 = es[p + h],     e1 = es[p + 2 + h];
            int2 e2 = es[p + 4 + h], e3 = es[p + 6 + h];
            uint v0 = h1u[(size_t)(e0.x & 0xFFFFFF) * 32 + fl];
            uint v1 = h1u[(size_t)(e1.x & 0xFFFFFF) * 32 + fl];
            uint v2 = h1u[(size_t)(e2.x & 0xFFFFFF) * 32 + fl];
            uint v3 = h1u[(size_t)(e3.x & 0xFFFFFF) * 32 + fl];
            float w0 = __int_as_float(e0.y), w1 = __int_as_float(e1.y);
            float w2 = __int_as_float(e2.y), w3 = __int_as_float(e3.y);
            ax += __uint_as_float(v0 << 16) * w0 + __uint_as_float(v1 << 16) * w1
                + __uint_as_float(v2 << 16) * w2 + __uint_as_float(v3 << 16) * w3;
            ay += __uint_as_float(v0 & 0xFFFF0000u) * w0 + __uint_as_float(v1 & 0xFFFF0000u) * w1
                + __uint_as_float(v2 & 0xFFFF0000u) * w2 + __uint_as_float(v3 & 0xFFFF0000u) * w3;
        }
        for (; p < pend; p += 2) {
            if (p + h < pend) {
                int2 e = es[p + h];
                uint v = h1u[(size_t)(e.x & 0xFFFFFF) * 32 + fl];
                float w = __int_as_float(e.y);
                ax += __uint_as_float(v << 16) * w;
                ay += __uint_as_float(v & 0xFFFF0000u) * w;
            }
        }
        ax += __shfl_xor(ax, 32, 64);
        ay += __shfl_xor(ay, 32, 64);
        if (h == 0) {   // write bf16 t-row (packed uint store)
            uint tx = (uint)f2bf(fmaxf(ax + b1s[2*fl],     0.f));
            uint ty = (uint)f2bf(fmaxf(ay + b1s[2*fl + 1], 0.f));
            tsu[(wave*16 + i) * 36 + fl] = tx | (ty << 16);
        }
    }
    // layer2 MFMA on this wave's own 16 rows (intra-wave LDS dep, in-order)
    const int m = lane & 15, quad = lane >> 4;
    floatx4 acc[2] = {(floatx4)(0.f), (floatx4)(0.f)};
    #pragma unroll
    for (int step = 0; step < 2; step++) {
        short8 a = *(const short8*)&ts[wave*16 + m][step*32 + quad*8];
        #pragma unroll
        for (int nt = 0; nt < 2; nt++) {
            short8 b = *(const short8*)&wf2[nt][step][lane][0];
            acc[nt] = __builtin_amdgcn_mfma_f32_16x16x32_bf16(a, b, acc[nt], 0, 0, 0);
        }
    }
    #pragma unroll
    for (int nt = 0; nt < 2; nt++) {
        #pragma unroll
        for (int r = 0; r < 4; r++) {
            int g = node0 + quad*4 + r;
            if (g < N) h2[(size_t)g*32 + nt*16 + m] = f2bf(acc[nt][r]);
        }
    }
}

// ------- gather2 batched: 16 nodes/wave, 16 lanes/edge, offsets prefetched ---
__global__ __launch_bounds__(256) void gather2_kernel(
    const u16* __restrict__ h2, const int2* __restrict__ es,
    const int* __restrict__ off, const float* __restrict__ b2,
    float* __restrict__ out, int N)
{
    const int tid = threadIdx.x;
    const int wave = tid >> 6, lane = tid & 63;
    const int q = lane >> 4, fl = lane & 15;
    const int node0 = blockIdx.x * 64 + wave * 16;
    const uint* h2u = (const uint*)h2;     // h2 row = 16 uints (32 bf16)

    const int segoff = off[min(node0 + min(lane, 16), N)];
    const float2 bb = *(const float2*)&b2[2 * fl];

    #pragma unroll 1
    for (int i = 0; i < 16; i++) {
        const int pbeg = __builtin_amdgcn_readlane(segoff, i);
        const int pend = __builtin_amdgcn_readlane(segoff, i + 1);
        float ax = 0.f, ay = 0.f;
        int p = pbeg;
        for (; p + 8 <= pend; p += 8) {    // 8 edges/iter, 2 gathers/lane
            int2 ea = es[p + q], eb = es[p + 4 + q];
            uint va = h2u[(size_t)(ea.x & 0xFFFFFF) * 16 + fl];
            uint vb = h2u[(size_t)(eb.x & 0xFFFFFF) * 16 + fl];
            float wa = __int_as_float(ea.y), wb = __int_as_float(eb.y);
            ax += __uint_as_float(va << 16) * wa + __uint_as_float(vb << 16) * wb;
            ay += __uint_as_float(va & 0xFFFF0000u) * wa + __uint_as_float(vb & 0xFFFF0000u) * wb;
        }
        for (; p < pend; p += 4) {
            if (p + q < pend) {
                int2 e = es[p + q];
                uint v = h2u[(size_t)(e.x & 0xFFFFFF) * 16 + fl];
                float w = __int_as_float(e.y);
                ax += __uint_as_float(v << 16) * w;
                ay += __uint_as_float(v & 0xFFFF0000u) * w;
            }
        }
        ax += __shfl_xor(ax, 16, 64); ay += __shfl_xor(ay, 16, 64);
        ax += __shfl_xor(ax, 32, 64); ay += __shfl_xor(ay, 32, 64);
        const int d = node0 + i;
        if (q == 0 && d < N)
            *(float2*)&out[(size_t)d * 32 + 2 * fl] = make_float2(ax + bb.x, ay + bb.y);
    }
}

extern "C" void kernel_launch(void* const* d_in, const int* in_sizes, int n_in,
                              void* d_out, int out_size, void* d_ws, size_t ws_size,
                              hipStream_t stream)
{
    const float* x   = (const float*)d_in[0];
    const int*  esrc = (const int*)d_in[1];
    const int*  edst = (const int*)d_in[2];
    const float* ew  = (const float*)d_in[3];
    const float* W1  = (const float*)d_in[4];
    const float* b1  = (const float*)d_in[5];
    const float* W2  = (const float*)d_in[6];
    const float* b2  = (const float*)d_in[7];
    float* out = (float*)d_out;

    const int N = in_sizes[0] / 128;   // 100000
    const int E = in_sizes[1];         // 1600000
    const int nb = (N + 255) >> 8;     // 391 buckets

    char* base = (char*)d_ws;
    size_t o = 0;
    auto alloc = [&](size_t bytes) { char* p = base + o; o = (o + bytes + 255) & ~(size_t)255; return p; };
    u16*  h1      = (u16*) alloc((size_t)N * 64 * 2);
    u16*  h2      = (u16*) alloc((size_t)N * 32 * 2);
    int2* es      = (int2*)alloc((size_t)E * 8);
    int2* es2     = (int2*)alloc((size_t)E * 8);
    int*  off     = (int*) alloc((size_t)(N + 1) * 4);
    int*  counts  = (int*) alloc(512 * 4);
    int*  boff    = (int*) alloc(512 * 4);
    int*  gcursor = (int*) alloc(512 * 4);

    const int gblocks = (N + 63) / 64;           // 1563 gemm blocks
    const int hblocks = (E + 1023) / 1024;       // 1563 hist blocks

    hipMemsetAsync(counts, 0, 512 * 4, stream);
    g1h_kernel<<<gblocks + hblocks, 256, 0, stream>>>(x, W1, h1, N, edst, counts, E, gblocks);
    bucket_scan<<<1, 512, 0, stream>>>(counts, boff, gcursor, nb);
    partition_kernel<<<(E + CHUNK - 1) / CHUNK, 512, 0, stream>>>(esrc, edst, ew, gcursor, es, E);
    sort2_kernel<<<nb, 512, 0, stream>>>(es, boff, es2, off, N, nb);
    gather1_kernel<<<(N + 63) / 64, 256, 0, stream>>>(h1, es2, off, b1, W2, h2, N);
    gather2_kernel<<<(N + 63) / 64, 256, 0, stream>>>(h2, es2, off, b2, out, N);
}

// Round 10
// 242.929 us; speedup vs baseline: 1.3315x; 1.1060x over previous
//
#include <hip/hip_runtime.h>
#include <hip/hip_bf16.h>

// GCN 2-layer, slack-bucket dst-radix-sort + batched wave gathers:
//   fused dispatch: blocks [0,pblocks) partition edges into slack bucket
//     regions (b*cap, alloc via gcursor atomics); blocks [pblocks,..) do
//     h1 = bf16(bf16(x) @ bf16(W1)) via MFMA 16x16x32
//   sort2: per-bucket counting sort by dst&255 -> es2 (+ per-node int2 seg)
//   gather1 (batched): wave gathers 16 nodes; layer2 (relu+b1)@W2 via MFMA
//   gather2 (batched): out = segsum(h2[src]*w) + b2 (f32)

typedef unsigned short u16;
typedef unsigned int uint;
typedef short short8 __attribute__((ext_vector_type(8)));
typedef float floatx4 __attribute__((ext_vector_type(4)));

static __device__ __forceinline__ u16 f2bf(float f) {
    unsigned int u = __float_as_uint(f);
    return (u16)((u + 0x7fff + ((u >> 16) & 1)) >> 16);   // RNE
}

#define F4C(v, j) ((j)==0?(v).x:((j)==1?(v).y:((j)==2?(v).z:(v).w)))
#define CHUNK 4096

// ------- fused: partition (blocks 0..pblocks-1) + GEMM h1=x@W1 (rest) -------
// edge entry: x = src | (dst&255)<<24 ; y = w bits
union SharedU {
    struct {                                   // GEMM part (33.4 KB)
        u16 xs[64][136];
        u16 wf[4][4][64][8];                   // [ntile][step][lane][j]
    } g;
    struct {                                   // partition part (50 KB)
        int2 stage[CHUNK];                     // 32 KB
        u16  stb[CHUNK];                       // 8 KB
        int  hist[512], sc[512], xscan[512], place[512], runbase[512];
    } p;
};

__global__ __launch_bounds__(256, 3) void g1p_kernel(
    const float* __restrict__ x, const float* __restrict__ W1,
    u16* __restrict__ h1, int N,
    const int* __restrict__ src, const int* __restrict__ dst,
    const float* __restrict__ w, int* __restrict__ gcursor,
    int2* __restrict__ es, int E, int cap, int pblocks)
{
    __shared__ SharedU sh;
    const int tid = threadIdx.x;

    if (blockIdx.x < pblocks) {            // ---------- partition ----------
        const int base = blockIdx.x * CHUNK;
        const int nloc = min(CHUNK, E - base);

        sh.p.hist[tid] = 0; sh.p.hist[tid + 256] = 0;
        __syncthreads();
        for (int i = tid; i < nloc; i += 256)
            atomicAdd(&sh.p.hist[dst[base + i] >> 8], 1);
        __syncthreads();

        sh.p.sc[tid] = sh.p.hist[tid];
        sh.p.sc[tid + 256] = sh.p.hist[tid + 256];
        __syncthreads();
        for (int o = 1; o < 512; o <<= 1) {          // inclusive scan, 512 wide
            int v0 = (tid >= o) ? sh.p.sc[tid - o] : 0;
            int v1 = (tid + 256 >= o) ? sh.p.sc[tid + 256 - o] : 0;
            __syncthreads();
            sh.p.sc[tid] += v0;
            sh.p.sc[tid + 256] += v1;
            __syncthreads();
        }
        sh.p.xscan[tid] = sh.p.sc[tid] - sh.p.hist[tid];
        sh.p.xscan[tid + 256] = sh.p.sc[tid + 256] - sh.p.hist[tid + 256];
        sh.p.place[tid] = sh.p.xscan[tid];
        sh.p.place[tid + 256] = sh.p.xscan[tid + 256];
        __syncthreads();

        for (int i = tid; i < nloc; i += 256) {      // group by bucket in LDS
            int d = dst[base + i];
            int b = d >> 8;
            int pos = atomicAdd(&sh.p.place[b], 1);
            sh.p.stage[pos] = make_int2(src[base + i] | ((d & 255) << 24),
                                        __float_as_int(w[base + i]));
            sh.p.stb[pos] = (u16)b;
        }
        __syncthreads();

        {   // reserve runs in slack regions
            int l0 = sh.p.hist[tid], l1 = sh.p.hist[tid + 256];
            sh.p.runbase[tid]       = l0 ? atomicAdd(&gcursor[tid], l0)       : 0;
            sh.p.runbase[tid + 256] = l1 ? atomicAdd(&gcursor[tid + 256], l1) : 0;
        }
        __syncthreads();

        for (int i = tid; i < nloc; i += 256) {      // contiguous run writes
            int b = sh.p.stb[i];
            es[(size_t)b * cap + sh.p.runbase[b] + (i - sh.p.xscan[b])] = sh.p.stage[i];
        }
        return;
    }

    // ---------- GEMM ----------
    const int row0 = (blockIdx.x - pblocks) * 64;
    {   // stage W1 (128x64 f32) -> bf16, swizzled to B-fragment order
        const float4* W4 = (const float4*)W1;
        #pragma unroll
        for (int i = 0; i < 8; i++) {
            int idx = tid + i*256;
            int k = idx >> 4, n4 = (idx & 15) * 4;
            float4 v = W4[idx];
            int step = k >> 5, klane = (k >> 3) & 3, j = k & 7;
            #pragma unroll
            for (int c = 0; c < 4; c++) {
                int n = n4 + c;
                sh.g.wf[n >> 4][step][klane*16 + (n & 15)][j] = f2bf(F4C(v, c));
            }
        }
    }
    {   // stage x tile -> bf16
        const float4* x4 = (const float4*)x;
        #pragma unroll
        for (int i = 0; i < 8; i++) {
            int idx = tid + i*256;
            int r = idx >> 5, kc = idx & 31;
            int gr = row0 + r;
            float4 v = make_float4(0.f,0.f,0.f,0.f);
            if (gr < N) v = x4[gr*32 + kc];
            ushort4 o;
            o.x = f2bf(v.x); o.y = f2bf(v.y); o.z = f2bf(v.z); o.w = f2bf(v.w);
            *(ushort4*)&sh.g.xs[r][kc*4] = o;
        }
    }
    __syncthreads();

    const int wave = tid >> 6, lane = tid & 63;
    const int m = lane & 15, quad = lane >> 4;
    const int rw = wave * 16;

    floatx4 acc[4] = {(floatx4)(0.f), (floatx4)(0.f), (floatx4)(0.f), (floatx4)(0.f)};
    #pragma unroll
    for (int step = 0; step < 4; step++) {
        short8 a = *(const short8*)&sh.g.xs[rw + m][step*32 + quad*8];
        #pragma unroll
        for (int nt = 0; nt < 4; nt++) {
            short8 b = *(const short8*)&sh.g.wf[nt][step][lane][0];
            acc[nt] = __builtin_amdgcn_mfma_f32_16x16x32_bf16(a, b, acc[nt], 0, 0, 0);
        }
    }
    #pragma unroll
    for (int nt = 0; nt < 4; nt++) {
        #pragma unroll
        for (int r = 0; r < 4; r++) {
            int gr = row0 + rw + quad*4 + r;
            if (gr < N) h1[(size_t)gr*64 + nt*16 + m] = f2bf(acc[nt][r]);
        }
    }
}

// ------- sort2: per-bucket single-pass counting sort (LDS-staged) -------
#define SCAP 6144
__global__ __launch_bounds__(512, 3) void sort2_kernel(
    const int2* __restrict__ es, const int* __restrict__ gcursor,
    int2* __restrict__ es2, int2* __restrict__ off2, int N, int cap, int nb)
{
    __shared__ int2 stage[SCAP];                  // 48 KB
    __shared__ int hist[256], sc[256], cur[256];
    const int t = threadIdx.x;
    const int b = blockIdx.x;
    const int e0 = b * cap;
    const int len = gcursor[b];
    const int nstage = min(len, SCAP);

    if (t < 256) hist[t] = 0;
    __syncthreads();
    for (int i = t; i < nstage; i += 512) {       // stage + hist in one pass
        int2 e = es[e0 + i];
        stage[i] = e;
        atomicAdd(&hist[((unsigned)e.x) >> 24], 1);
    }
    for (int i = SCAP + t; i < len; i += 512)     // overflow: hist from global
        atomicAdd(&hist[((unsigned)es[e0 + i].x) >> 24], 1);
    __syncthreads();

    int v = 0;
    if (t < 256) { v = hist[t]; sc[t] = v; }
    __syncthreads();
    for (int o = 1; o < 256; o <<= 1) {
        int add = 0;
        if (t < 256 && t >= o) add = sc[t - o];
        __syncthreads();
        if (t < 256) sc[t] += add;
        __syncthreads();
    }
    if (t < 256) {
        int ex = sc[t] - v;                       // exclusive within bucket
        cur[t] = ex;
        int g = b * 256 + t;
        if (g < N) off2[g] = make_int2(e0 + ex, e0 + ex + v);
    }
    __syncthreads();

    for (int i = t; i < nstage; i += 512) {
        int2 e = stage[i];
        int pos = e0 + atomicAdd(&cur[((unsigned)e.x) >> 24], 1);
        es2[pos] = e;                             // scatter within 36 KB window
    }
    for (int i = SCAP + t; i < len; i += 512) {   // overflow scatter
        int2 e = es[e0 + i];
        int pos = e0 + atomicAdd(&cur[((unsigned)e.x) >> 24], 1);
        es2[pos] = e;
    }
}

// ------- gather1 batched: 64 nodes/block, wave gathers 16 nodes -> LDS bf16
//         segments prefetched (int2); layer2 (relu(+b1) @ W2) via MFMA ----
__global__ __launch_bounds__(256) void gather1_kernel(
    const u16* __restrict__ h1, const int2* __restrict__ es,
    const int2* __restrict__ off2, const float* __restrict__ b1,
    const float* __restrict__ W2, u16* __restrict__ h2, int N)
{
    __shared__ __align__(16) u16 ts[64][72];          // t rows, bf16 (144B rows)
    __shared__ __align__(16) u16 wf2[2][2][64][8];    // [ntile][step][lane][j]
    __shared__ float b1s[64];
    const int tid = threadIdx.x;

    {   // stage W2 (64x32 f32 = 512 float4) -> bf16 B-fragments, + b1
        const float4* s4 = (const float4*)W2;
        #pragma unroll
        for (int i = 0; i < 2; i++) {
            int idx = tid + i*256;
            float4 v = s4[idx];
            int k = idx >> 3, n4 = (idx & 7) * 4;
            int step = k >> 5, quad = (k >> 3) & 3, j = k & 7;
            #pragma unroll
            for (int c = 0; c < 4; c++) {
                int n = n4 + c;
                wf2[n >> 4][step][quad*16 + (n & 15)][j] = f2bf(F4C(v, c));
            }
        }
        if (tid < 16) ((float4*)b1s)[tid] = ((const float4*)b1)[tid];
    }
    __syncthreads();

    const int wave = tid >> 6, lane = tid & 63;
    const int h = lane >> 5, fl = lane & 31;
    const int node0 = blockIdx.x * 64 + wave * 16;
    const uint* h1u = (const uint*)h1;     // h1 row = 32 uints (64 bf16)
    uint* tsu = (uint*)&ts[0][0];          // rows of 36 uints

    // prefetch this wave's 16 segments (lanes 0..15 hold int2)
    const int gseg = node0 + (lane & 15);
    const int2 sg = (gseg < N) ? off2[gseg] : make_int2(0, 0);

    #pragma unroll 1
    for (int i = 0; i < 16; i++) {
        const int pbeg = __builtin_amdgcn_readlane(sg.x, i);
        const int pend = __builtin_amdgcn_readlane(sg.y, i);
        float ax = 0.f, ay = 0.f;
        int p = pbeg;
        for (; p + 8 <= pend; p += 8) {    // 8 edges/iter, 4 gathers in flight
            int2 e0 = es[p + h],     e1 = es[p + 2 + h];
            int2 e2 = es[p + 4 + h], e3 = es[p + 6 + h];
            uint v0 = h1u[(size_t)(e0.x & 0xFFFFFF) * 32 + fl];
            uint v1 = h1u[(size_t)(e1.x & 0xFFFFFF) * 32 + fl];
            uint v2 = h1u[(size_t)(e2.x & 0xFFFFFF) * 32 + fl];
            uint v3 = h1u[(size_t)(e3.x & 0xFFFFFF) * 32 + fl];
            float w0 = __int_as_float(e0.y), w1 = __int_as_float(e1.y);
            float w2 = __int_as_float(e2.y), w3 = __int_as_float(e3.y);
            ax += __uint_as_float(v0 << 16) * w0 + __uint_as_float(v1 << 16) * w1
                + __uint_as_float(v2 << 16) * w2 + __uint_as_float(v3 << 16) * w3;
            ay += __uint_as_float(v0 & 0xFFFF0000u) * w0 + __uint_as_float(v1 & 0xFFFF0000u) * w1
                + __uint_as_float(v2 & 0xFFFF0000u) * w2 + __uint_as_float(v3 & 0xFFFF0000u) * w3;
        }
        for (; p < pend; p += 2) {
            if (p + h < pend) {
                int2 e = es[p + h];
                uint v = h1u[(size_t)(e.x & 0xFFFFFF) * 32 + fl];
                float w = __int_as_float(e.y);
                ax += __uint_as_float(v << 16) * w;
                ay += __uint_as_float(v & 0xFFFF0000u) * w;
            }
        }
        ax += __shfl_xor(ax, 32, 64);
        ay += __shfl_xor(ay, 32, 64);
        if (h == 0) {   // write bf16 t-row (packed uint store)
            uint tx = (uint)f2bf(fmaxf(ax + b1s[2*fl],     0.f));
            uint ty = (uint)f2bf(fmaxf(ay + b1s[2*fl + 1], 0.f));
            tsu[(wave*16 + i) * 36 + fl] = tx | (ty << 16);
        }
    }
    // layer2 MFMA on this wave's own 16 rows (intra-wave LDS dep, in-order)
    const int m = lane & 15, quad = lane >> 4;
    floatx4 acc[2] = {(floatx4)(0.f), (floatx4)(0.f)};
    #pragma unroll
    for (int step = 0; step < 2; step++) {
        short8 a = *(const short8*)&ts[wave*16 + m][step*32 + quad*8];
        #pragma unroll
        for (int nt = 0; nt < 2; nt++) {
            short8 b = *(const short8*)&wf2[nt][step][lane][0];
            acc[nt] = __builtin_amdgcn_mfma_f32_16x16x32_bf16(a, b, acc[nt], 0, 0, 0);
        }
    }
    #pragma unroll
    for (int nt = 0; nt < 2; nt++) {
        #pragma unroll
        for (int r = 0; r < 4; r++) {
            int g = node0 + quad*4 + r;
            if (g < N) h2[(size_t)g*32 + nt*16 + m] = f2bf(acc[nt][r]);
        }
    }
}

// ------- gather2 batched: 16 nodes/wave, 16 lanes/edge, segments prefetched --
__global__ __launch_bounds__(256) void gather2_kernel(
    const u16* __restrict__ h2, const int2* __restrict__ es,
    const int2* __restrict__ off2, const float* __restrict__ b2,
    float* __restrict__ out, int N)
{
    const int tid = threadIdx.x;
    const int wave = tid >> 6, lane = tid & 63;
    const int q = lane >> 4, fl = lane & 15;
    const int node0 = blockIdx.x * 64 + wave * 16;
    const uint* h2u = (const uint*)h2;     // h2 row = 16 uints (32 bf16)

    const int gseg = node0 + (lane & 15);
    const int2 sg = (gseg < N) ? off2[gseg] : make_int2(0, 0);
    const float2 bb = *(const float2*)&b2[2 * fl];

    #pragma unroll 1
    for (int i = 0; i < 16; i++) {
        const int pbeg = __builtin_amdgcn_readlane(sg.x, i);
        const int pend = __builtin_amdgcn_readlane(sg.y, i);
        float ax = 0.f, ay = 0.f;
        int p = pbeg;
        for (; p + 8 <= pend; p += 8) {    // 8 edges/iter, 2 gathers/lane
            int2 ea = es[p + q], eb = es[p + 4 + q];
            uint va = h2u[(size_t)(ea.x & 0xFFFFFF) * 16 + fl];
            uint vb = h2u[(size_t)(eb.x & 0xFFFFFF) * 16 + fl];
            float wa = __int_as_float(ea.y), wb = __int_as_float(eb.y);
            ax += __uint_as_float(va << 16) * wa + __uint_as_float(vb << 16) * wb;
            ay += __uint_as_float(va & 0xFFFF0000u) * wa + __uint_as_float(vb & 0xFFFF0000u) * wb;
        }
        for (; p < pend; p += 4) {
            if (p + q < pend) {
                int2 e = es[p + q];
                uint v = h2u[(size_t)(e.x & 0xFFFFFF) * 16 + fl];
                float w = __int_as_float(e.y);
                ax += __uint_as_float(v << 16) * w;
                ay += __uint_as_float(v & 0xFFFF0000u) * w;
            }
        }
        ax += __shfl_xor(ax, 16, 64); ay += __shfl_xor(ay, 16, 64);
        ax += __shfl_xor(ax, 32, 64); ay += __shfl_xor(ay, 32, 64);
        const int d = node0 + i;
        if (q == 0 && d < N)
            *(float2*)&out[(size_t)d * 32 + 2 * fl] = make_float2(ax + bb.x, ay + bb.y);
    }
}

extern "C" void kernel_launch(void* const* d_in, const int* in_sizes, int n_in,
                              void* d_out, int out_size, void* d_ws, size_t ws_size,
                              hipStream_t stream)
{
    const float* x   = (const float*)d_in[0];
    const int*  esrc = (const int*)d_in[1];
    const int*  edst = (const int*)d_in[2];
    const float* ew  = (const float*)d_in[3];
    const float* W1  = (const float*)d_in[4];
    const float* b1  = (const float*)d_in[5];
    const float* W2  = (const float*)d_in[6];
    const float* b2  = (const float*)d_in[7];
    float* out = (float*)d_out;

    const int N = in_sizes[0] / 128;   // 100000
    const int E = in_sizes[1];         // 1600000
    const int nb = (N + 255) >> 8;     // 391 buckets

    // slack bucket capacity: mean + ~8 sigma, 16-aligned
    const int mean = (E + nb - 1) / nb;
    int s = 1; while (s * s < mean) s++;                  // ceil sqrt
    const int cap = (mean + 8 * s + 15) & ~15;            // ~4608

    char* base = (char*)d_ws;
    size_t o = 0;
    auto alloc = [&](size_t bytes) { char* p = base + o; o = (o + bytes + 255) & ~(size_t)255; return p; };
    u16*  h1      = (u16*) alloc((size_t)N * 64 * 2);
    u16*  h2      = (u16*) alloc((size_t)N * 32 * 2);
    int2* es      = (int2*)alloc((size_t)nb * cap * 8);
    int2* es2     = (int2*)alloc((size_t)nb * cap * 8);
    int2* off2    = (int2*)alloc((size_t)N * 8);
    int*  gcursor = (int*) alloc(512 * 4);

    const int pblocks = (E + CHUNK - 1) / CHUNK;   // 391 partition blocks
    const int gblocks = (N + 63) / 64;             // 1563 gemm blocks

    hipMemsetAsync(gcursor, 0, 512 * 4, stream);
    g1p_kernel<<<pblocks + gblocks, 256, 0, stream>>>(
        x, W1, h1, N, esrc, edst, ew, gcursor, es, E, cap, pblocks);
    sort2_kernel<<<nb, 512, 0, stream>>>(es, gcursor, es2, off2, N, cap, nb);
    gather1_kernel<<<(N + 63) / 64, 256, 0, stream>>>(h1, es2, off2, b1, W2, h2, N);
    gather2_kernel<<<(N + 63) / 64, 256, 0, stream>>>(h2, es2, off2, b2, out, N);
}

// Round 11
// 238.311 us; speedup vs baseline: 1.3573x; 1.0194x over previous
//
#include <hip/hip_runtime.h>
#include <hip/hip_bf16.h>

// GCN 2-layer, slack-bucket dst-radix-sort + batched wave gathers:
//   fused dispatch: blocks [0,pblocks) partition edges into slack bucket
//     regions (b*cap, alloc via gcursor atomics); blocks [pblocks,..) do
//     h1 = bf16(bf16(x) @ bf16(W1)) via MFMA 16x16x32
//   sort2: per-bucket counting sort by dst&255 -> es2 (+ per-node int2 seg)
//   gather1 (batched, LDS edge staging): wave gathers 16 nodes; layer2 via MFMA
//   gather2 (batched, LDS edge staging): out = segsum(h2[src]*w) + b2 (f32)

typedef unsigned short u16;
typedef unsigned int uint;
typedef short short8 __attribute__((ext_vector_type(8)));
typedef float floatx4 __attribute__((ext_vector_type(4)));

static __device__ __forceinline__ u16 f2bf(float f) {
    unsigned int u = __float_as_uint(f);
    return (u16)((u + 0x7fff + ((u >> 16) & 1)) >> 16);   // RNE
}

#define F4C(v, j) ((j)==0?(v).x:((j)==1?(v).y:((j)==2?(v).z:(v).w)))
#define CHUNK 4096
#define ECAP 448   // per-wave LDS edge-buffer capacity (mean 256, +12 sigma)

// ------- fused: partition (blocks 0..pblocks-1) + GEMM h1=x@W1 (rest) -------
// edge entry: x = src | (dst&255)<<24 ; y = w bits
union SharedU {
    struct {                                   // GEMM part (33.4 KB)
        u16 xs[64][136];
        u16 wf[4][4][64][8];                   // [ntile][step][lane][j]
    } g;
    struct {                                   // partition part (50 KB)
        int2 stage[CHUNK];                     // 32 KB
        u16  stb[CHUNK];                       // 8 KB
        int  hist[512], sc[512], xscan[512], place[512], runbase[512];
    } p;
};

__global__ __launch_bounds__(256, 3) void g1p_kernel(
    const float* __restrict__ x, const float* __restrict__ W1,
    u16* __restrict__ h1, int N,
    const int* __restrict__ src, const int* __restrict__ dst,
    const float* __restrict__ w, int* __restrict__ gcursor,
    int2* __restrict__ es, int E, int cap, int pblocks)
{
    __shared__ SharedU sh;
    const int tid = threadIdx.x;

    if (blockIdx.x < pblocks) {            // ---------- partition ----------
        const int base = blockIdx.x * CHUNK;
        const int nloc = min(CHUNK, E - base);

        sh.p.hist[tid] = 0; sh.p.hist[tid + 256] = 0;
        __syncthreads();
        for (int i = tid; i < nloc; i += 256)
            atomicAdd(&sh.p.hist[dst[base + i] >> 8], 1);
        __syncthreads();

        sh.p.sc[tid] = sh.p.hist[tid];
        sh.p.sc[tid + 256] = sh.p.hist[tid + 256];
        __syncthreads();
        for (int o = 1; o < 512; o <<= 1) {          // inclusive scan, 512 wide
            int v0 = (tid >= o) ? sh.p.sc[tid - o] : 0;
            int v1 = (tid + 256 >= o) ? sh.p.sc[tid + 256 - o] : 0;
            __syncthreads();
            sh.p.sc[tid] += v0;
            sh.p.sc[tid + 256] += v1;
            __syncthreads();
        }
        sh.p.xscan[tid] = sh.p.sc[tid] - sh.p.hist[tid];
        sh.p.xscan[tid + 256] = sh.p.sc[tid + 256] - sh.p.hist[tid + 256];
        sh.p.place[tid] = sh.p.xscan[tid];
        sh.p.place[tid + 256] = sh.p.xscan[tid + 256];
        __syncthreads();

        for (int i = tid; i < nloc; i += 256) {      // group by bucket in LDS
            int d = dst[base + i];
            int b = d >> 8;
            int pos = atomicAdd(&sh.p.place[b], 1);
            sh.p.stage[pos] = make_int2(src[base + i] | ((d & 255) << 24),
                                        __float_as_int(w[base + i]));
            sh.p.stb[pos] = (u16)b;
        }
        __syncthreads();

        {   // reserve runs in slack regions
            int l0 = sh.p.hist[tid], l1 = sh.p.hist[tid + 256];
            sh.p.runbase[tid]       = l0 ? atomicAdd(&gcursor[tid], l0)       : 0;
            sh.p.runbase[tid + 256] = l1 ? atomicAdd(&gcursor[tid + 256], l1) : 0;
        }
        __syncthreads();

        for (int i = tid; i < nloc; i += 256) {      // contiguous run writes
            int b = sh.p.stb[i];
            es[(size_t)b * cap + sh.p.runbase[b] + (i - sh.p.xscan[b])] = sh.p.stage[i];
        }
        return;
    }

    // ---------- GEMM ----------
    const int row0 = (blockIdx.x - pblocks) * 64;
    {   // stage W1 (128x64 f32) -> bf16, swizzled to B-fragment order
        const float4* W4 = (const float4*)W1;
        #pragma unroll
        for (int i = 0; i < 8; i++) {
            int idx = tid + i*256;
            int k = idx >> 4, n4 = (idx & 15) * 4;
            float4 v = W4[idx];
            int step = k >> 5, klane = (k >> 3) & 3, j = k & 7;
            #pragma unroll
            for (int c = 0; c < 4; c++) {
                int n = n4 + c;
                sh.g.wf[n >> 4][step][klane*16 + (n & 15)][j] = f2bf(F4C(v, c));
            }
        }
    }
    {   // stage x tile -> bf16
        const float4* x4 = (const float4*)x;
        #pragma unroll
        for (int i = 0; i < 8; i++) {
            int idx = tid + i*256;
            int r = idx >> 5, kc = idx & 31;
            int gr = row0 + r;
            float4 v = make_float4(0.f,0.f,0.f,0.f);
            if (gr < N) v = x4[gr*32 + kc];
            ushort4 o;
            o.x = f2bf(v.x); o.y = f2bf(v.y); o.z = f2bf(v.z); o.w = f2bf(v.w);
            *(ushort4*)&sh.g.xs[r][kc*4] = o;
        }
    }
    __syncthreads();

    const int wave = tid >> 6, lane = tid & 63;
    const int m = lane & 15, quad = lane >> 4;
    const int rw = wave * 16;

    floatx4 acc[4] = {(floatx4)(0.f), (floatx4)(0.f), (floatx4)(0.f), (floatx4)(0.f)};
    #pragma unroll
    for (int step = 0; step < 4; step++) {
        short8 a = *(const short8*)&sh.g.xs[rw + m][step*32 + quad*8];
        #pragma unroll
        for (int nt = 0; nt < 4; nt++) {
            short8 b = *(const short8*)&sh.g.wf[nt][step][lane][0];
            acc[nt] = __builtin_amdgcn_mfma_f32_16x16x32_bf16(a, b, acc[nt], 0, 0, 0);
        }
    }
    #pragma unroll
    for (int nt = 0; nt < 4; nt++) {
        #pragma unroll
        for (int r = 0; r < 4; r++) {
            int gr = row0 + rw + quad*4 + r;
            if (gr < N) h1[(size_t)gr*64 + nt*16 + m] = f2bf(acc[nt][r]);
        }
    }
}

// ------- sort2: per-bucket single-pass counting sort (LDS-staged) -------
#define SCAP 6144
__global__ __launch_bounds__(512, 3) void sort2_kernel(
    const int2* __restrict__ es, const int* __restrict__ gcursor,
    int2* __restrict__ es2, int2* __restrict__ off2, int N, int cap, int nb)
{
    __shared__ int2 stage[SCAP];                  // 48 KB
    __shared__ int hist[256], sc[256], cur[256];
    const int t = threadIdx.x;
    const int b = blockIdx.x;
    const int e0 = b * cap;
    const int len = gcursor[b];
    const int nstage = min(len, SCAP);

    if (t < 256) hist[t] = 0;
    __syncthreads();
    for (int i = t; i < nstage; i += 512) {       // stage + hist in one pass
        int2 e = es[e0 + i];
        stage[i] = e;
        atomicAdd(&hist[((unsigned)e.x) >> 24], 1);
    }
    for (int i = SCAP + t; i < len; i += 512)     // overflow: hist from global
        atomicAdd(&hist[((unsigned)es[e0 + i].x) >> 24], 1);
    __syncthreads();

    int v = 0;
    if (t < 256) { v = hist[t]; sc[t] = v; }
    __syncthreads();
    for (int o = 1; o < 256; o <<= 1) {
        int add = 0;
        if (t < 256 && t >= o) add = sc[t - o];
        __syncthreads();
        if (t < 256) sc[t] += add;
        __syncthreads();
    }
    if (t < 256) {
        int ex = sc[t] - v;                       // exclusive within bucket
        cur[t] = ex;
        int g = b * 256 + t;
        if (g < N) off2[g] = make_int2(e0 + ex, e0 + ex + v);
    }
    __syncthreads();

    for (int i = t; i < nstage; i += 512) {
        int2 e = stage[i];
        int pos = e0 + atomicAdd(&cur[((unsigned)e.x) >> 24], 1);
        es2[pos] = e;                             // scatter within 36 KB window
    }
    for (int i = SCAP + t; i < len; i += 512) {   // overflow scatter
        int2 e = es[e0 + i];
        int pos = e0 + atomicAdd(&cur[((unsigned)e.x) >> 24], 1);
        es2[pos] = e;
    }
}

// ------- gather1 batched: 64 nodes/block, wave stages its contiguous edge
//         range into LDS, gathers 16 nodes; layer2 (relu(+b1) @ W2) via MFMA --
__global__ __launch_bounds__(256) void gather1_kernel(
    const u16* __restrict__ h1, const int2* __restrict__ es,
    const int2* __restrict__ off2, const float* __restrict__ b1,
    const float* __restrict__ W2, u16* __restrict__ h2, int N)
{
    __shared__ __align__(16) u16 ts[64][72];          // t rows, bf16 (144B rows)
    __shared__ __align__(16) u16 wf2[2][2][64][8];    // [ntile][step][lane][j]
    __shared__ float b1s[64];
    __shared__ int2 eb[4][ECAP];                      // per-wave edge buffer
    const int tid = threadIdx.x;

    {   // stage W2 (64x32 f32 = 512 float4) -> bf16 B-fragments, + b1
        const float4* s4 = (const float4*)W2;
        #pragma unroll
        for (int i = 0; i < 2; i++) {
            int idx = tid + i*256;
            float4 v = s4[idx];
            int k = idx >> 3, n4 = (idx & 7) * 4;
            int step = k >> 5, quad = (k >> 3) & 3, j = k & 7;
            #pragma unroll
            for (int c = 0; c < 4; c++) {
                int n = n4 + c;
                wf2[n >> 4][step][quad*16 + (n & 15)][j] = f2bf(F4C(v, c));
            }
        }
        if (tid < 16) ((float4*)b1s)[tid] = ((const float4*)b1)[tid];
    }
    __syncthreads();

    const int wave = tid >> 6, lane = tid & 63;
    const int h = lane >> 5, fl = lane & 31;
    const int node0 = blockIdx.x * 64 + wave * 16;
    const uint* h1u = (const uint*)h1;     // h1 row = 32 uints (64 bf16)
    uint* tsu = (uint*)&ts[0][0];          // rows of 36 uints

    // prefetch segments (lanes 0..15; clamp keeps OOB waves harmless)
    const int2 sg = off2[min(node0 + (lane & 15), N - 1)];
    const int beg = __builtin_amdgcn_readfirstlane(sg.x);
    const int end = __builtin_amdgcn_readlane(sg.y, 15);
    const int len = end - beg;

    if (len <= ECAP) {
        // ---- stage wave's whole edge range into LDS (coalesced) ----
        for (int k = lane; k < len; k += 64) eb[wave][k] = es[beg + k];
        // intra-wave LDS write->read ordering: compiler lgkmcnt

        #pragma unroll 1
        for (int i = 0; i < 16; i++) {
            const int pbeg = __builtin_amdgcn_readlane(sg.x, i) - beg;
            const int pend = __builtin_amdgcn_readlane(sg.y, i) - beg;
            float ax = 0.f, ay = 0.f;
            int p = pbeg;
            for (; p + 8 <= pend; p += 8) {    // 8 edges/iter, 4 gathers in flight
                int2 e0 = eb[wave][p + h],     e1 = eb[wave][p + 2 + h];
                int2 e2 = eb[wave][p + 4 + h], e3 = eb[wave][p + 6 + h];
                uint v0 = h1u[(size_t)(e0.x & 0xFFFFFF) * 32 + fl];
                uint v1 = h1u[(size_t)(e1.x & 0xFFFFFF) * 32 + fl];
                uint v2 = h1u[(size_t)(e2.x & 0xFFFFFF) * 32 + fl];
                uint v3 = h1u[(size_t)(e3.x & 0xFFFFFF) * 32 + fl];
                float w0 = __int_as_float(e0.y), w1 = __int_as_float(e1.y);
                float w2 = __int_as_float(e2.y), w3 = __int_as_float(e3.y);
                ax += __uint_as_float(v0 << 16) * w0 + __uint_as_float(v1 << 16) * w1
                    + __uint_as_float(v2 << 16) * w2 + __uint_as_float(v3 << 16) * w3;
                ay += __uint_as_float(v0 & 0xFFFF0000u) * w0 + __uint_as_float(v1 & 0xFFFF0000u) * w1
                    + __uint_as_float(v2 & 0xFFFF0000u) * w2 + __uint_as_float(v3 & 0xFFFF0000u) * w3;
            }
            for (; p < pend; p += 2) {
                if (p + h < pend) {
                    int2 e = eb[wave][p + h];
                    uint v = h1u[(size_t)(e.x & 0xFFFFFF) * 32 + fl];
                    float w = __int_as_float(e.y);
                    ax += __uint_as_float(v << 16) * w;
                    ay += __uint_as_float(v & 0xFFFF0000u) * w;
                }
            }
            ax += __shfl_xor(ax, 32, 64);
            ay += __shfl_xor(ay, 32, 64);
            if (h == 0) {
                uint tx = (uint)f2bf(fmaxf(ax + b1s[2*fl],     0.f));
                uint ty = (uint)f2bf(fmaxf(ay + b1s[2*fl + 1], 0.f));
                tsu[(wave*16 + i) * 36 + fl] = tx | (ty << 16);
            }
        }
    } else {
        // ---- overflow fallback: direct global edge reads (never in practice)
        #pragma unroll 1
        for (int i = 0; i < 16; i++) {
            const int pbeg = __builtin_amdgcn_readlane(sg.x, i);
            const int pend = __builtin_amdgcn_readlane(sg.y, i);
            float ax = 0.f, ay = 0.f;
            int p = pbeg;
            for (; p + 8 <= pend; p += 8) {
                int2 e0 = es[p + h],     e1 = es[p + 2 + h];
                int2 e2 = es[p + 4 + h], e3 = es[p + 6 + h];
                uint v0 = h1u[(size_t)(e0.x & 0xFFFFFF) * 32 + fl];
                uint v1 = h1u[(size_t)(e1.x & 0xFFFFFF) * 32 + fl];
                uint v2 = h1u[(size_t)(e2.x & 0xFFFFFF) * 32 + fl];
                uint v3 = h1u[(size_t)(e3.x & 0xFFFFFF) * 32 + fl];
                float w0 = __int_as_float(e0.y), w1 = __int_as_float(e1.y);
                float w2 = __int_as_float(e2.y), w3 = __int_as_float(e3.y);
                ax += __uint_as_float(v0 << 16) * w0 + __uint_as_float(v1 << 16) * w1
                    + __uint_as_float(v2 << 16) * w2 + __uint_as_float(v3 << 16) * w3;
                ay += __uint_as_float(v0 & 0xFFFF0000u) * w0 + __uint_as_float(v1 & 0xFFFF0000u) * w1
                    + __uint_as_float(v2 & 0xFFFF0000u) * w2 + __uint_as_float(v3 & 0xFFFF0000u) * w3;
            }
            for (; p < pend; p += 2) {
                if (p + h < pend) {
                    int2 e = es[p + h];
                    uint v = h1u[(size_t)(e.x & 0xFFFFFF) * 32 + fl];
                    float w = __int_as_float(e.y);
                    ax += __uint_as_float(v << 16) * w;
                    ay += __uint_as_float(v & 0xFFFF0000u) * w;
                }
            }
            ax += __shfl_xor(ax, 32, 64);
            ay += __shfl_xor(ay, 32, 64);
            if (h == 0) {
                uint tx = (uint)f2bf(fmaxf(ax + b1s[2*fl],     0.f));
                uint ty = (uint)f2bf(fmaxf(ay + b1s[2*fl + 1], 0.f));
                tsu[(wave*16 + i) * 36 + fl] = tx | (ty << 16);
            }
        }
    }

    // layer2 MFMA on this wave's own 16 rows (intra-wave LDS dep, in-order)
    const int m = lane & 15, quad = lane >> 4;
    floatx4 acc[2] = {(floatx4)(0.f), (floatx4)(0.f)};
    #pragma unroll
    for (int step = 0; step < 2; step++) {
        short8 a = *(const short8*)&ts[wave*16 + m][step*32 + quad*8];
        #pragma unroll
        for (int nt = 0; nt < 2; nt++) {
            short8 b = *(const short8*)&wf2[nt][step][lane][0];
            acc[nt] = __builtin_amdgcn_mfma_f32_16x16x32_bf16(a, b, acc[nt], 0, 0, 0);
        }
    }
    #pragma unroll
    for (int nt = 0; nt < 2; nt++) {
        #pragma unroll
        for (int r = 0; r < 4; r++) {
            int g = node0 + quad*4 + r;
            if (g < N) h2[(size_t)g*32 + nt*16 + m] = f2bf(acc[nt][r]);
        }
    }
}

// ------- gather2 batched: 16 nodes/wave, LDS edge staging, 16 lanes/edge ----
__global__ __launch_bounds__(256) void gather2_kernel(
    const u16* __restrict__ h2, const int2* __restrict__ es,
    const int2* __restrict__ off2, const float* __restrict__ b2,
    float* __restrict__ out, int N)
{
    __shared__ int2 eb[4][ECAP];
    const int tid = threadIdx.x;
    const int wave = tid >> 6, lane = tid & 63;
    const int q = lane >> 4, fl = lane & 15;
    const int node0 = blockIdx.x * 64 + wave * 16;
    const uint* h2u = (const uint*)h2;     // h2 row = 16 uints (32 bf16)

    const int2 sg = off2[min(node0 + (lane & 15), N - 1)];
    const int beg = __builtin_amdgcn_readfirstlane(sg.x);
    const int end = __builtin_amdgcn_readlane(sg.y, 15);
    const int len = end - beg;
    const float2 bb = *(const float2*)&b2[2 * fl];

    if (len <= ECAP) {
        for (int k = lane; k < len; k += 64) eb[wave][k] = es[beg + k];

        #pragma unroll 1
        for (int i = 0; i < 16; i++) {
            const int pbeg = __builtin_amdgcn_readlane(sg.x, i) - beg;
            const int pend = __builtin_amdgcn_readlane(sg.y, i) - beg;
            float ax = 0.f, ay = 0.f;
            int p = pbeg;
            for (; p + 8 <= pend; p += 8) {    // 8 edges/iter, 2 gathers/lane
                int2 ea = eb[wave][p + q], ebv = eb[wave][p + 4 + q];
                uint va = h2u[(size_t)(ea.x & 0xFFFFFF) * 16 + fl];
                uint vb = h2u[(size_t)(ebv.x & 0xFFFFFF) * 16 + fl];
                float wa = __int_as_float(ea.y), wb = __int_as_float(ebv.y);
                ax += __uint_as_float(va << 16) * wa + __uint_as_float(vb << 16) * wb;
                ay += __uint_as_float(va & 0xFFFF0000u) * wa + __uint_as_float(vb & 0xFFFF0000u) * wb;
            }
            for (; p < pend; p += 4) {
                if (p + q < pend) {
                    int2 e = eb[wave][p + q];
                    uint v = h2u[(size_t)(e.x & 0xFFFFFF) * 16 + fl];
                    float w = __int_as_float(e.y);
                    ax += __uint_as_float(v << 16) * w;
                    ay += __uint_as_float(v & 0xFFFF0000u) * w;
                }
            }
            ax += __shfl_xor(ax, 16, 64); ay += __shfl_xor(ay, 16, 64);
            ax += __shfl_xor(ax, 32, 64); ay += __shfl_xor(ay, 32, 64);
            const int d = node0 + i;
            if (q == 0 && d < N)
                *(float2*)&out[(size_t)d * 32 + 2 * fl] = make_float2(ax + bb.x, ay + bb.y);
        }
    } else {
        #pragma unroll 1
        for (int i = 0; i < 16; i++) {
            const int pbeg = __builtin_amdgcn_readlane(sg.x, i);
            const int pend = __builtin_amdgcn_readlane(sg.y, i);
            float ax = 0.f, ay = 0.f;
            int p = pbeg;
            for (; p + 8 <= pend; p += 8) {
                int2 ea = es[p + q], ebv = es[p + 4 + q];
                uint va = h2u[(size_t)(ea.x & 0xFFFFFF) * 16 + fl];
                uint vb = h2u[(size_t)(ebv.x & 0xFFFFFF) * 16 + fl];
                float wa = __int_as_float(ea.y), wb = __int_as_float(ebv.y);
                ax += __uint_as_float(va << 16) * wa + __uint_as_float(vb << 16) * wb;
                ay += __uint_as_float(va & 0xFFFF0000u) * wa + __uint_as_float(vb & 0xFFFF0000u) * wb;
            }
            for (; p < pend; p += 4) {
                if (p + q < pend) {
                    int2 e = es[p + q];
                    uint v = h2u[(size_t)(e.x & 0xFFFFFF) * 16 + fl];
                    float w = __int_as_float(e.y);
                    ax += __uint_as_float(v << 16) * w;
                    ay += __uint_as_float(v & 0xFFFF0000u) * w;
                }
            }
            ax += __shfl_xor(ax, 16, 64); ay += __shfl_xor(ay, 16, 64);
            ax += __shfl_xor(ax, 32, 64); ay += __shfl_xor(ay, 32, 64);
            const int d = node0 + i;
            if (q == 0 && d < N)
                *(float2*)&out[(size_t)d * 32 + 2 * fl] = make_float2(ax + bb.x, ay + bb.y);
        }
    }
}

extern "C" void kernel_launch(void* const* d_in, const int* in_sizes, int n_in,
                              void* d_out, int out_size, void* d_ws, size_t ws_size,
                              hipStream_t stream)
{
    const float* x   = (const float*)d_in[0];
    const int*  esrc = (const int*)d_in[1];
    const int*  edst = (const int*)d_in[2];
    const float* ew  = (const float*)d_in[3];
    const float* W1  = (const float*)d_in[4];
    const float* b1  = (const float*)d_in[5];
    const float* W2  = (const float*)d_in[6];
    const float* b2  = (const float*)d_in[7];
    float* out = (float*)d_out;

    const int N = in_sizes[0] / 128;   // 100000
    const int E = in_sizes[1];         // 1600000
    const int nb = (N + 255) >> 8;     // 391 buckets

    // slack bucket capacity: mean + ~8 sigma, 16-aligned
    const int mean = (E + nb - 1) / nb;
    int s = 1; while (s * s < mean) s++;                  // ceil sqrt
    const int cap = (mean + 8 * s + 15) & ~15;            // ~4608

    char* base = (char*)d_ws;
    size_t o = 0;
    auto alloc = [&](size_t bytes) { char* p = base + o; o = (o + bytes + 255) & ~(size_t)255; return p; };
    u16*  h1      = (u16*) alloc((size_t)N * 64 * 2);
    u16*  h2      = (u16*) alloc((size_t)N * 32 * 2);
    int2* es      = (int2*)alloc((size_t)nb * cap * 8);
    int2* es2     = (int2*)alloc((size_t)nb * cap * 8);
    int2* off2    = (int2*)alloc((size_t)N * 8);
    int*  gcursor = (int*) alloc(512 * 4);

    const int pblocks = (E + CHUNK - 1) / CHUNK;   // 391 partition blocks
    const int gblocks = (N + 63) / 64;             // 1563 gemm blocks

    hipMemsetAsync(gcursor, 0, 512 * 4, stream);
    g1p_kernel<<<pblocks + gblocks, 256, 0, stream>>>(
        x, W1, h1, N, esrc, edst, ew, gcursor, es, E, cap, pblocks);
    sort2_kernel<<<nb, 512, 0, stream>>>(es, gcursor, es2, off2, N, cap, nb);
    gather1_kernel<<<(N + 63) / 64, 256, 0, stream>>>(h1, es2, off2, b1, W2, h2, N);
    gather2_kernel<<<(N + 63) / 64, 256, 0, stream>>>(h2, es2, off2, b2, out, N);
}